// Round 4
// baseline (1844.404 us; speedup 1.0000x reference)
//
#include <hip/hip_runtime.h>
#include <stdint.h>

// LSTM autoencoder B=32768 T=30 I=4 H=64 L=32. ALL tensors fp32 (v4).
// v3 post-mortem: threshold = exactly 2% * max|ref| (bf16 floor inactive)
// => no bf16 anywhere; output buffer is fp32. v4 = v3 + fp32 output stores.
// Weights staged to LDS as fp32 in TWO PHASES (encoder, then decoder
// re-staged into the same region). Wave = 4 batch elems.
//  enc1/dec1: lane j = unit j, 4 gates, RB=4 batches (mvAF).
//  enc2:      lane j=lane&31 = unit j, 4 gates, 2 batches (mvCF).
//  dec2:      lane (q=lane&15, r=lane>>4) computes gate-row q for batch r.

typedef unsigned short u16;
typedef unsigned int u32;

#define BATCH 32768
#define TT 30
#define IN 4
#define RB 4
#define WAVES 16
#define BLOCK (WAVES * 64)
#define BPB (WAVES * RB)   // 64 batches per block

// fp32 weight region (shared by both phases), word = float
//  enc: W1ih 1024 | W1hh 16384 | W2ih 8192 | W2hh 4096   -> 29696
//  dec: W3ih 8192 | W3hh 16384 | W4ih 16*68=1088 | W4hh 64 -> 25728
#define WREG 29696
#define E_W1IH 0
#define E_W1HH 1024
#define E_W2IH 17408
#define E_W2HH 25600
#define D_W3IH 0
#define D_W3HH 8192
#define D_W4IH 24576
#define D_W4HH 25664

#define NBIAS (256 + 128 + 256 + 16)   // 656 floats
#define BUFW 464   // per-wave floats: 256 bufX + 128 bufY + 16 bufH4 + 64 gbuf
#define SMEM_WORDS (WREG + NBIAS + WAVES * BUFW)   // 37776
#define SMEM_BYTES (SMEM_WORDS * 4)                // 151104 <= 163840

__device__ __forceinline__ float sigf(float x) {
    x = fminf(fmaxf(x, -30.f), 30.f);
    return 1.f / (1.f + __expf(-x));
}
__device__ __forceinline__ float tanh_(float x) {
    x = fminf(fmaxf(x, -15.f), 15.f);
    const float t = __expf(2.f * x);
    return (t - 1.f) / (t + 1.f);
}

// W[4*Hh, K] row-major fp32 -> dst[(k*Hh + j)*4 + g] = W[g*Hh + j][k]
__device__ __forceinline__ void loadPackF(float* dst, const float* src, int K, int Hh, int tid) {
    const int n = K * Hh * 4;
    for (int idx = tid; idx < n; idx += BLOCK) {
        const int g = idx & 3;
        const int j = (idx >> 2) & (Hh - 1);   // Hh is 32 or 64 (pow2)
        const int k = idx / (4 * Hh);
        dst[idx] = src[(g * Hh + j) * K + k];
    }
}

// Hh=64: lane j owns unit j, 4 gates, RB batches. acc[g][r] += W[g*64+j,:] . hin[r*K..]
template <int K>
__device__ __forceinline__ void mvAF(const float* W, const float* hin, int lane,
                                     float (&acc)[4][RB]) {
#pragma unroll 2
    for (int k4 = 0; k4 < K / 4; ++k4) {
        float hh[RB][4];
#pragma unroll
        for (int r = 0; r < RB; ++r) {
            const float4 hv = *reinterpret_cast<const float4*>(hin + r * K + 4 * k4);
            hh[r][0] = hv.x; hh[r][1] = hv.y; hh[r][2] = hv.z; hh[r][3] = hv.w;
        }
#pragma unroll
        for (int kk = 0; kk < 4; ++kk) {
            const float4 w = *reinterpret_cast<const float4*>(W + ((4 * k4 + kk) * 64 + lane) * 4);
#pragma unroll
            for (int r = 0; r < RB; ++r) {
                acc[0][r] = fmaf(w.x, hh[r][kk], acc[0][r]);
                acc[1][r] = fmaf(w.y, hh[r][kk], acc[1][r]);
                acc[2][r] = fmaf(w.z, hh[r][kk], acc[2][r]);
                acc[3][r] = fmaf(w.w, hh[r][kk], acc[3][r]);
            }
        }
    }
}

// Hh=32: lane j (=lane&31) owns unit j, 4 gates, 2 batches (rows hin, hin+K)
template <int K>
__device__ __forceinline__ void mvCF(const float* W, const float* hin, int j,
                                     float (&acc)[4][2]) {
#pragma unroll 2
    for (int k4 = 0; k4 < K / 4; ++k4) {
        const float4 h0 = *reinterpret_cast<const float4*>(hin + 4 * k4);
        const float4 h1 = *reinterpret_cast<const float4*>(hin + K + 4 * k4);
        const float ha[4] = {h0.x, h0.y, h0.z, h0.w};
        const float hb[4] = {h1.x, h1.y, h1.z, h1.w};
#pragma unroll
        for (int kk = 0; kk < 4; ++kk) {
            const float4 w = *reinterpret_cast<const float4*>(W + ((4 * k4 + kk) * 32 + j) * 4);
            acc[0][0] = fmaf(w.x, ha[kk], acc[0][0]);
            acc[1][0] = fmaf(w.y, ha[kk], acc[1][0]);
            acc[2][0] = fmaf(w.z, ha[kk], acc[2][0]);
            acc[3][0] = fmaf(w.w, ha[kk], acc[3][0]);
            acc[0][1] = fmaf(w.x, hb[kk], acc[0][1]);
            acc[1][1] = fmaf(w.y, hb[kk], acc[1][1]);
            acc[2][1] = fmaf(w.z, hb[kk], acc[2][1]);
            acc[3][1] = fmaf(w.w, hb[kk], acc[3][1]);
        }
    }
}

__global__ __launch_bounds__(BLOCK) void lstm_ae(
    const float* __restrict__ x,
    const float* __restrict__ w1ih, const float* __restrict__ w1hh,
    const float* __restrict__ b1i, const float* __restrict__ b1h,
    const float* __restrict__ w2ih, const float* __restrict__ w2hh,
    const float* __restrict__ b2i, const float* __restrict__ b2h,
    const float* __restrict__ w3ih, const float* __restrict__ w3hh,
    const float* __restrict__ b3i, const float* __restrict__ b3h,
    const float* __restrict__ w4ih, const float* __restrict__ w4hh,
    const float* __restrict__ b4i, const float* __restrict__ b4h,
    float* __restrict__ out) {
    extern __shared__ float smem[];
    float* W = smem;                       // WREG: phase-dependent weights
    float* bias1 = smem + WREG;
    float* bias2 = bias1 + 256;
    float* bias3 = bias2 + 128;
    float* bias4 = bias3 + 256;
    float* bufs = bias4 + 16;

    const int tid = threadIdx.x;
    const int wave = tid >> 6, lane = tid & 63;
    float* wbuf = bufs + wave * BUFW;
    float* bufX = wbuf;            // [4][64]  h1 / h3
    float* bufY = wbuf + 256;      // [4][32]  h2 / latent
    float* bufH4 = wbuf + 384;     // [4][4]   h4
    float* gbuf = wbuf + 400;      // [4][16]  dec2 pre-activations
    const int b0 = blockIdx.x * BPB + wave * RB;

    // ---------- stage ENCODER weights + all biases ----------
    loadPackF(W + E_W1IH, w1ih, 4, 64, tid);
    loadPackF(W + E_W1HH, w1hh, 64, 64, tid);
    loadPackF(W + E_W2IH, w2ih, 64, 32, tid);
    loadPackF(W + E_W2HH, w2hh, 32, 32, tid);
    for (int i = tid; i < 256; i += BLOCK) bias1[i] = b1i[i] + b1h[i];
    for (int i = tid; i < 128; i += BLOCK) bias2[i] = b2i[i] + b2h[i];
    for (int i = tid; i < 256; i += BLOCK) bias3[i] = b3i[i] + b3h[i];
    for (int i = tid; i < 16; i += BLOCK) bias4[i] = b4i[i] + b4h[i];

    // encoder state init
#pragma unroll
    for (int r = 0; r < RB; ++r) bufX[r * 64 + lane] = 0.f;
    {
        const int j = lane & 31;
        const int rb = (lane >> 5) * 2;
        bufY[(rb + 0) * 32 + j] = 0.f;
        bufY[(rb + 1) * 32 + j] = 0.f;
    }
    __syncthreads();   // staging + init visible

    // per-lane biases
    float br1[4], br3[4], br2[4];
#pragma unroll
    for (int g = 0; g < 4; ++g) {
        br1[g] = bias1[g * 64 + lane];
        br3[g] = bias3[g * 64 + lane];
        br2[g] = bias2[g * 32 + (lane & 31)];
    }
    const float br4 = bias4[lane & 15];

    // ================= encoder =================
    const int j2 = lane & 31;
    const int rb2 = (lane >> 5) * 2;
    float c1[RB], c2[2];
#pragma unroll
    for (int r = 0; r < RB; ++r) c1[r] = 0.f;
    c2[0] = 0.f; c2[1] = 0.f;

    for (int t = 0; t < TT; ++t) {
        float xf[RB][4];
#pragma unroll
        for (int r = 0; r < RB; ++r) {
            const float4 xv = *reinterpret_cast<const float4*>(x + ((size_t)(b0 + r) * TT + t) * IN);
            xf[r][0] = xv.x; xf[r][1] = xv.y; xf[r][2] = xv.z; xf[r][3] = xv.w;
        }
        // ---- enc1 ----
        float a1[4][RB];
#pragma unroll
        for (int g = 0; g < 4; ++g)
#pragma unroll
            for (int r = 0; r < RB; ++r) a1[g][r] = br1[g];
#pragma unroll
        for (int k = 0; k < 4; ++k) {   // Wih, K=4
            const float4 w = *reinterpret_cast<const float4*>(W + E_W1IH + (k * 64 + lane) * 4);
#pragma unroll
            for (int r = 0; r < RB; ++r) {
                a1[0][r] = fmaf(w.x, xf[r][k], a1[0][r]);
                a1[1][r] = fmaf(w.y, xf[r][k], a1[1][r]);
                a1[2][r] = fmaf(w.z, xf[r][k], a1[2][r]);
                a1[3][r] = fmaf(w.w, xf[r][k], a1[3][r]);
            }
        }
        mvAF<64>(W + E_W1HH, bufX, lane, a1);   // h1[t-1]
        float h1v[RB];
#pragma unroll
        for (int r = 0; r < RB; ++r) {
            const float iv = sigf(a1[0][r]), fv = sigf(a1[1][r]);
            const float gv = tanh_(a1[2][r]), ov = sigf(a1[3][r]);
            c1[r] = fv * c1[r] + iv * gv;
            h1v[r] = ov * tanh_(c1[r]);
        }
#pragma unroll
        for (int r = 0; r < RB; ++r) bufX[r * 64 + lane] = h1v[r];
        __syncthreads();   // h1[t] visible
        // ---- enc2 ----
        float a2[4][2];
#pragma unroll
        for (int g = 0; g < 4; ++g) { a2[g][0] = br2[g]; a2[g][1] = br2[g]; }
        mvCF<64>(W + E_W2IH, bufX + rb2 * 64, j2, a2);   // h1[t]
        mvCF<32>(W + E_W2HH, bufY + rb2 * 32, j2, a2);   // h2[t-1]
#pragma unroll
        for (int r2 = 0; r2 < 2; ++r2) {
            const float iv = sigf(a2[0][r2]), fv = sigf(a2[1][r2]);
            const float gv = tanh_(a2[2][r2]), ov = sigf(a2[3][r2]);
            c2[r2] = fv * c2[r2] + iv * gv;
            bufY[(rb2 + r2) * 32 + j2] = ov * tanh_(c2[r2]);
        }
        __syncthreads();   // h2[t] visible
    }
    // bufY = latent (h2 at t=29); read-only below.

    // ---------- re-stage DECODER weights ----------
    loadPackF(W + D_W3IH, w3ih, 32, 64, tid);
    loadPackF(W + D_W3HH, w3hh, 64, 64, tid);
    for (int idx = tid; idx < 16 * 64; idx += BLOCK) {   // W4ih [16,64] -> [q][k pad 68]
        const int q = idx >> 6, k = idx & 63;
        W[D_W4IH + q * 68 + k] = w4ih[q * 64 + k];
    }
    for (int idx = tid; idx < 64; idx += BLOCK)          // W4hh [16,4] row-major
        W[D_W4HH + idx] = w4hh[idx];

    // decoder state init
    const int q4 = lane & 15, r4 = lane >> 4;    // dec2 phase A task
    const int u4 = lane & 3, rr4 = lane >> 2;    // dec2 phase B task (lane<16)
    float c3[RB], c4 = 0.f;
#pragma unroll
    for (int r = 0; r < RB; ++r) c3[r] = 0.f;
#pragma unroll
    for (int r = 0; r < RB; ++r) bufX[r * 64 + lane] = 0.f;
    if (lane < 16) bufH4[rr4 * 4 + u4] = 0.f;
    __syncthreads();   // dec weights + init visible

    for (int t = 0; t < TT; ++t) {
        // ---- dec1 ----
        float a3[4][RB];
#pragma unroll
        for (int g = 0; g < 4; ++g)
#pragma unroll
            for (int r = 0; r < RB; ++r) a3[g][r] = br3[g];
        mvAF<32>(W + D_W3IH, bufY, lane, a3);   // latent
        mvAF<64>(W + D_W3HH, bufX, lane, a3);   // h3[t-1]
        float h3v[RB];
#pragma unroll
        for (int r = 0; r < RB; ++r) {
            const float iv = sigf(a3[0][r]), fv = sigf(a3[1][r]);
            const float gv = tanh_(a3[2][r]), ov = sigf(a3[3][r]);
            c3[r] = fv * c3[r] + iv * gv;
            h3v[r] = ov * tanh_(c3[r]);
        }
#pragma unroll
        for (int r = 0; r < RB; ++r) bufX[r * 64 + lane] = h3v[r];
        __syncthreads();   // h3[t] visible
        // ---- dec2 phase A: lane (q4, r4) computes gate-row q4 for batch r4 ----
        float a4 = br4;
#pragma unroll 4
        for (int k4 = 0; k4 < 16; ++k4) {
            const float4 w = *reinterpret_cast<const float4*>(W + D_W4IH + q4 * 68 + 4 * k4);
            const float4 h = *reinterpret_cast<const float4*>(bufX + r4 * 64 + 4 * k4);
            a4 = fmaf(w.x, h.x, a4);
            a4 = fmaf(w.y, h.y, a4);
            a4 = fmaf(w.z, h.z, a4);
            a4 = fmaf(w.w, h.w, a4);
        }
        {
            const float4 wh = *reinterpret_cast<const float4*>(W + D_W4HH + q4 * 4);
            const float4 h4 = *reinterpret_cast<const float4*>(bufH4 + r4 * 4);   // h4[t-1]
            a4 = fmaf(wh.x, h4.x, a4);
            a4 = fmaf(wh.y, h4.y, a4);
            a4 = fmaf(wh.z, h4.z, a4);
            a4 = fmaf(wh.w, h4.w, a4);
        }
        gbuf[r4 * 16 + q4] = a4;
        __syncthreads();   // pre-activations visible
        // ---- dec2 phase B: lane<16, (u4, rr4): gates -> c4,h4, store out ----
        if (lane < 16) {
            const float iv = sigf(gbuf[rr4 * 16 + u4]);
            const float fv = sigf(gbuf[rr4 * 16 + 4 + u4]);
            const float gv = tanh_(gbuf[rr4 * 16 + 8 + u4]);
            const float ov = sigf(gbuf[rr4 * 16 + 12 + u4]);
            c4 = fv * c4 + iv * gv;
            const float h = ov * tanh_(c4);
            bufH4[rr4 * 4 + u4] = h;
            out[((size_t)(b0 + rr4) * TT + t) * IN + u4] = h;   // fp32 store
        }
        __syncthreads();   // h4[t] visible for next t
    }
}

extern "C" void kernel_launch(void* const* d_in, const int* in_sizes, int n_in,
                              void* d_out, int out_size, void* d_ws, size_t ws_size,
                              hipStream_t stream) {
    (void)in_sizes; (void)n_in; (void)d_ws; (void)ws_size; (void)out_size;
    hipFuncSetAttribute(reinterpret_cast<const void*>(lstm_ae),
                        hipFuncAttributeMaxDynamicSharedMemorySize, SMEM_BYTES);
    const float* xi = (const float*)d_in[0];
    const float* w1ih = (const float*)d_in[1];
    const float* w1hh = (const float*)d_in[2];
    const float* b1i = (const float*)d_in[3];
    const float* b1h = (const float*)d_in[4];
    const float* w2ih = (const float*)d_in[5];
    const float* w2hh = (const float*)d_in[6];
    const float* b2i = (const float*)d_in[7];
    const float* b2h = (const float*)d_in[8];
    const float* w3ih = (const float*)d_in[9];
    const float* w3hh = (const float*)d_in[10];
    const float* b3i = (const float*)d_in[11];
    const float* b3h = (const float*)d_in[12];
    const float* w4ih = (const float*)d_in[13];
    const float* w4hh = (const float*)d_in[14];
    const float* b4i = (const float*)d_in[15];
    const float* b4h = (const float*)d_in[16];
    float* out = (float*)d_out;

    lstm_ae<<<dim3(BATCH / BPB), dim3(BLOCK), SMEM_BYTES, stream>>>(
        xi, w1ih, w1hh, b1i, b1h, w2ih, w2hh, b2i, b2h,
        w3ih, w3hh, b3i, b3h, w4ih, w4hh, b4i, b4h, out);
}

// Round 5
// 1656.468 us; speedup vs baseline: 1.1135x; 1.1135x over previous
//
#include <hip/hip_runtime.h>
#include <stdint.h>

// LSTM autoencoder B=32768 T=30 I=4 H=64 L=32. ALL tensors fp32.
// v5 = v4 (passed, 1844us) with VALU-issue optimizations:
//  - sigmoid/tanh via v_rcp_f32 (NaN-safe forms, no clamps, no IEEE div seq)
//  - main recurrence loops use wave_barrier only (all LDS bufs are wave-private;
//    v1==v2 bit-identical proved wave-scope ordering is safe on this HW);
//    __syncthreads only around weight staging/re-staging.
//  - full unroll of matvec loops (immediate ds offsets, deep load hoisting)
//  - __launch_bounds__(1024,4): allow up to 128 VGPR (LDS caps at 4 waves/SIMD)

typedef unsigned short u16;
typedef unsigned int u32;

#define BATCH 32768
#define TT 30
#define IN 4
#define RB 4
#define WAVES 16
#define BLOCK (WAVES * 64)
#define BPB (WAVES * RB)   // 64 batches per block

// fp32 weight region (shared by both phases), word = float
//  enc: W1ih 1024 | W1hh 16384 | W2ih 8192 | W2hh 4096   -> 29696
//  dec: W3ih 8192 | W3hh 16384 | W4ih 16*68=1088 | W4hh 64 -> 25728
#define WREG 29696
#define E_W1IH 0
#define E_W1HH 1024
#define E_W2IH 17408
#define E_W2HH 25600
#define D_W3IH 0
#define D_W3HH 8192
#define D_W4IH 24576
#define D_W4HH 25664

#define NBIAS (256 + 128 + 256 + 16)   // 656 floats
#define BUFW 464   // per-wave floats: 256 bufX + 128 bufY + 16 bufH4 + 64 gbuf
#define SMEM_WORDS (WREG + NBIAS + WAVES * BUFW)   // 37776
#define SMEM_BYTES (SMEM_WORDS * 4)                // 151104 <= 163840

#define WB() __builtin_amdgcn_wave_barrier()

// sigmoid(x) = 1/(1+e^-x); rcp handles inf cleanly: x->-inf: rcp(inf)=0; x->+inf: rcp(1)=1
__device__ __forceinline__ float sigf(float x) {
    return __builtin_amdgcn_rcpf(1.f + __expf(-x));
}
// tanh(x) = 1 - 2/(e^2x + 1); t=inf -> 1; t=0 -> -1. NaN-free for all finite x.
__device__ __forceinline__ float tanh_(float x) {
    const float t = __expf(2.f * x);
    return fmaf(-2.f, __builtin_amdgcn_rcpf(t + 1.f), 1.f);
}

// W[4*Hh, K] row-major fp32 -> dst[(k*Hh + j)*4 + g] = W[g*Hh + j][k]
__device__ __forceinline__ void loadPackF(float* dst, const float* src, int K, int Hh, int tid) {
    const int n = K * Hh * 4;
    for (int idx = tid; idx < n; idx += BLOCK) {
        const int g = idx & 3;
        const int j = (idx >> 2) & (Hh - 1);   // Hh is 32 or 64 (pow2)
        const int k = idx / (4 * Hh);
        dst[idx] = src[(g * Hh + j) * K + k];
    }
}

// Hh=64: lane j owns unit j, 4 gates, RB batches. acc[g][r] += W[g*64+j,:] . hin[r*K..]
template <int K>
__device__ __forceinline__ void mvAF(const float* W, const float* hin, int lane,
                                     float (&acc)[4][RB]) {
#pragma unroll
    for (int k4 = 0; k4 < K / 4; ++k4) {
        float hh[RB][4];
#pragma unroll
        for (int r = 0; r < RB; ++r) {
            const float4 hv = *reinterpret_cast<const float4*>(hin + r * K + 4 * k4);
            hh[r][0] = hv.x; hh[r][1] = hv.y; hh[r][2] = hv.z; hh[r][3] = hv.w;
        }
#pragma unroll
        for (int kk = 0; kk < 4; ++kk) {
            const float4 w = *reinterpret_cast<const float4*>(W + ((4 * k4 + kk) * 64 + lane) * 4);
#pragma unroll
            for (int r = 0; r < RB; ++r) {
                acc[0][r] = fmaf(w.x, hh[r][kk], acc[0][r]);
                acc[1][r] = fmaf(w.y, hh[r][kk], acc[1][r]);
                acc[2][r] = fmaf(w.z, hh[r][kk], acc[2][r]);
                acc[3][r] = fmaf(w.w, hh[r][kk], acc[3][r]);
            }
        }
    }
}

// Hh=32: lane j (=lane&31) owns unit j, 4 gates, 2 batches (rows hin, hin+K)
template <int K>
__device__ __forceinline__ void mvCF(const float* W, const float* hin, int j,
                                     float (&acc)[4][2]) {
#pragma unroll
    for (int k4 = 0; k4 < K / 4; ++k4) {
        const float4 h0 = *reinterpret_cast<const float4*>(hin + 4 * k4);
        const float4 h1 = *reinterpret_cast<const float4*>(hin + K + 4 * k4);
        const float ha[4] = {h0.x, h0.y, h0.z, h0.w};
        const float hb[4] = {h1.x, h1.y, h1.z, h1.w};
#pragma unroll
        for (int kk = 0; kk < 4; ++kk) {
            const float4 w = *reinterpret_cast<const float4*>(W + ((4 * k4 + kk) * 32 + j) * 4);
            acc[0][0] = fmaf(w.x, ha[kk], acc[0][0]);
            acc[1][0] = fmaf(w.y, ha[kk], acc[1][0]);
            acc[2][0] = fmaf(w.z, ha[kk], acc[2][0]);
            acc[3][0] = fmaf(w.w, ha[kk], acc[3][0]);
            acc[0][1] = fmaf(w.x, hb[kk], acc[0][1]);
            acc[1][1] = fmaf(w.y, hb[kk], acc[1][1]);
            acc[2][1] = fmaf(w.z, hb[kk], acc[2][1]);
            acc[3][1] = fmaf(w.w, hb[kk], acc[3][1]);
        }
    }
}

__global__ __launch_bounds__(BLOCK, 4) void lstm_ae(
    const float* __restrict__ x,
    const float* __restrict__ w1ih, const float* __restrict__ w1hh,
    const float* __restrict__ b1i, const float* __restrict__ b1h,
    const float* __restrict__ w2ih, const float* __restrict__ w2hh,
    const float* __restrict__ b2i, const float* __restrict__ b2h,
    const float* __restrict__ w3ih, const float* __restrict__ w3hh,
    const float* __restrict__ b3i, const float* __restrict__ b3h,
    const float* __restrict__ w4ih, const float* __restrict__ w4hh,
    const float* __restrict__ b4i, const float* __restrict__ b4h,
    float* __restrict__ out) {
    extern __shared__ float smem[];
    float* W = smem;                       // WREG: phase-dependent weights
    float* bias1 = smem + WREG;
    float* bias2 = bias1 + 256;
    float* bias3 = bias2 + 128;
    float* bias4 = bias3 + 256;
    float* bufs = bias4 + 16;

    const int tid = threadIdx.x;
    const int wave = tid >> 6, lane = tid & 63;
    float* wbuf = bufs + wave * BUFW;
    float* bufX = wbuf;            // [4][64]  h1 / h3   (wave-private)
    float* bufY = wbuf + 256;      // [4][32]  h2 / latent
    float* bufH4 = wbuf + 384;     // [4][4]   h4
    float* gbuf = wbuf + 400;      // [4][16]  dec2 pre-activations
    const int b0 = blockIdx.x * BPB + wave * RB;

    // ---------- stage ENCODER weights + all biases ----------
    loadPackF(W + E_W1IH, w1ih, 4, 64, tid);
    loadPackF(W + E_W1HH, w1hh, 64, 64, tid);
    loadPackF(W + E_W2IH, w2ih, 64, 32, tid);
    loadPackF(W + E_W2HH, w2hh, 32, 32, tid);
    for (int i = tid; i < 256; i += BLOCK) bias1[i] = b1i[i] + b1h[i];
    for (int i = tid; i < 128; i += BLOCK) bias2[i] = b2i[i] + b2h[i];
    for (int i = tid; i < 256; i += BLOCK) bias3[i] = b3i[i] + b3h[i];
    for (int i = tid; i < 16; i += BLOCK) bias4[i] = b4i[i] + b4h[i];

    // encoder state init
#pragma unroll
    for (int r = 0; r < RB; ++r) bufX[r * 64 + lane] = 0.f;
    {
        const int j = lane & 31;
        const int rb = (lane >> 5) * 2;
        bufY[(rb + 0) * 32 + j] = 0.f;
        bufY[(rb + 1) * 32 + j] = 0.f;
    }
    __syncthreads();   // staging + init visible (block-wide: W region is shared)

    // per-lane biases
    float br1[4], br3[4], br2[4];
#pragma unroll
    for (int g = 0; g < 4; ++g) {
        br1[g] = bias1[g * 64 + lane];
        br3[g] = bias3[g * 64 + lane];
        br2[g] = bias2[g * 32 + (lane & 31)];
    }
    const float br4 = bias4[lane & 15];

    // ================= encoder =================
    const int j2 = lane & 31;
    const int rb2 = (lane >> 5) * 2;
    float c1[RB], c2[2];
#pragma unroll
    for (int r = 0; r < RB; ++r) c1[r] = 0.f;
    c2[0] = 0.f; c2[1] = 0.f;

    for (int t = 0; t < TT; ++t) {
        float xf[RB][4];
#pragma unroll
        for (int r = 0; r < RB; ++r) {
            const float4 xv = *reinterpret_cast<const float4*>(x + ((size_t)(b0 + r) * TT + t) * IN);
            xf[r][0] = xv.x; xf[r][1] = xv.y; xf[r][2] = xv.z; xf[r][3] = xv.w;
        }
        // ---- enc1 ----
        float a1[4][RB];
#pragma unroll
        for (int g = 0; g < 4; ++g)
#pragma unroll
            for (int r = 0; r < RB; ++r) a1[g][r] = br1[g];
#pragma unroll
        for (int k = 0; k < 4; ++k) {   // Wih, K=4
            const float4 w = *reinterpret_cast<const float4*>(W + E_W1IH + (k * 64 + lane) * 4);
#pragma unroll
            for (int r = 0; r < RB; ++r) {
                a1[0][r] = fmaf(w.x, xf[r][k], a1[0][r]);
                a1[1][r] = fmaf(w.y, xf[r][k], a1[1][r]);
                a1[2][r] = fmaf(w.z, xf[r][k], a1[2][r]);
                a1[3][r] = fmaf(w.w, xf[r][k], a1[3][r]);
            }
        }
        mvAF<64>(W + E_W1HH, bufX, lane, a1);   // h1[t-1]
        float h1v[RB];
#pragma unroll
        for (int r = 0; r < RB; ++r) {
            const float iv = sigf(a1[0][r]), fv = sigf(a1[1][r]);
            const float gv = tanh_(a1[2][r]), ov = sigf(a1[3][r]);
            c1[r] = fv * c1[r] + iv * gv;
            h1v[r] = ov * tanh_(c1[r]);
        }
        WB();
#pragma unroll
        for (int r = 0; r < RB; ++r) bufX[r * 64 + lane] = h1v[r];
        WB();   // h1[t] visible (wave-private; DS pipe is in-order per wave)
        // ---- enc2 ----
        float a2[4][2];
#pragma unroll
        for (int g = 0; g < 4; ++g) { a2[g][0] = br2[g]; a2[g][1] = br2[g]; }
        mvCF<64>(W + E_W2IH, bufX + rb2 * 64, j2, a2);   // h1[t]
        mvCF<32>(W + E_W2HH, bufY + rb2 * 32, j2, a2);   // h2[t-1]
        WB();
#pragma unroll
        for (int r2 = 0; r2 < 2; ++r2) {
            const float iv = sigf(a2[0][r2]), fv = sigf(a2[1][r2]);
            const float gv = tanh_(a2[2][r2]), ov = sigf(a2[3][r2]);
            c2[r2] = fv * c2[r2] + iv * gv;
            bufY[(rb2 + r2) * 32 + j2] = ov * tanh_(c2[r2]);
        }
        WB();   // h2[t] visible
    }
    // bufY = latent (h2 at t=29); read-only below.

    __syncthreads();   // ALL waves out of encoder before overwriting W region

    // ---------- re-stage DECODER weights ----------
    loadPackF(W + D_W3IH, w3ih, 32, 64, tid);
    loadPackF(W + D_W3HH, w3hh, 64, 64, tid);
    for (int idx = tid; idx < 16 * 64; idx += BLOCK) {   // W4ih [16,64] -> [q][k pad 68]
        const int q = idx >> 6, k = idx & 63;
        W[D_W4IH + q * 68 + k] = w4ih[q * 64 + k];
    }
    for (int idx = tid; idx < 64; idx += BLOCK)          // W4hh [16,4] row-major
        W[D_W4HH + idx] = w4hh[idx];

    // decoder state init
    const int q4 = lane & 15, r4 = lane >> 4;    // dec2 phase A task
    const int u4 = lane & 3, rr4 = lane >> 2;    // dec2 phase B task (lane<16)
    float c3[RB], c4 = 0.f;
#pragma unroll
    for (int r = 0; r < RB; ++r) c3[r] = 0.f;
#pragma unroll
    for (int r = 0; r < RB; ++r) bufX[r * 64 + lane] = 0.f;
    if (lane < 16) bufH4[rr4 * 4 + u4] = 0.f;
    __syncthreads();   // dec weights + init visible

    for (int t = 0; t < TT; ++t) {
        // ---- dec1 ----
        float a3[4][RB];
#pragma unroll
        for (int g = 0; g < 4; ++g)
#pragma unroll
            for (int r = 0; r < RB; ++r) a3[g][r] = br3[g];
        mvAF<32>(W + D_W3IH, bufY, lane, a3);   // latent
        mvAF<64>(W + D_W3HH, bufX, lane, a3);   // h3[t-1]
        float h3v[RB];
#pragma unroll
        for (int r = 0; r < RB; ++r) {
            const float iv = sigf(a3[0][r]), fv = sigf(a3[1][r]);
            const float gv = tanh_(a3[2][r]), ov = sigf(a3[3][r]);
            c3[r] = fv * c3[r] + iv * gv;
            h3v[r] = ov * tanh_(c3[r]);
        }
        WB();
#pragma unroll
        for (int r = 0; r < RB; ++r) bufX[r * 64 + lane] = h3v[r];
        WB();   // h3[t] visible
        // ---- dec2 phase A: lane (q4, r4) computes gate-row q4 for batch r4 ----
        float a4 = br4;
#pragma unroll
        for (int k4 = 0; k4 < 16; ++k4) {
            const float4 w = *reinterpret_cast<const float4*>(W + D_W4IH + q4 * 68 + 4 * k4);
            const float4 h = *reinterpret_cast<const float4*>(bufX + r4 * 64 + 4 * k4);
            a4 = fmaf(w.x, h.x, a4);
            a4 = fmaf(w.y, h.y, a4);
            a4 = fmaf(w.z, h.z, a4);
            a4 = fmaf(w.w, h.w, a4);
        }
        {
            const float4 wh = *reinterpret_cast<const float4*>(W + D_W4HH + q4 * 4);
            const float4 h4 = *reinterpret_cast<const float4*>(bufH4 + r4 * 4);   // h4[t-1]
            a4 = fmaf(wh.x, h4.x, a4);
            a4 = fmaf(wh.y, h4.y, a4);
            a4 = fmaf(wh.z, h4.z, a4);
            a4 = fmaf(wh.w, h4.w, a4);
        }
        WB();
        gbuf[r4 * 16 + q4] = a4;
        WB();   // pre-activations visible
        // ---- dec2 phase B: lane<16, (u4, rr4): gates -> c4,h4, store out ----
        if (lane < 16) {
            const float iv = sigf(gbuf[rr4 * 16 + u4]);
            const float fv = sigf(gbuf[rr4 * 16 + 4 + u4]);
            const float gv = tanh_(gbuf[rr4 * 16 + 8 + u4]);
            const float ov = sigf(gbuf[rr4 * 16 + 12 + u4]);
            c4 = fv * c4 + iv * gv;
            const float h = ov * tanh_(c4);
            bufH4[rr4 * 4 + u4] = h;
            out[((size_t)(b0 + rr4) * TT + t) * IN + u4] = h;   // fp32 store
        }
        WB();   // h4[t] visible for next t
    }
}

extern "C" void kernel_launch(void* const* d_in, const int* in_sizes, int n_in,
                              void* d_out, int out_size, void* d_ws, size_t ws_size,
                              hipStream_t stream) {
    (void)in_sizes; (void)n_in; (void)d_ws; (void)ws_size; (void)out_size;
    hipFuncSetAttribute(reinterpret_cast<const void*>(lstm_ae),
                        hipFuncAttributeMaxDynamicSharedMemorySize, SMEM_BYTES);
    const float* xi = (const float*)d_in[0];
    const float* w1ih = (const float*)d_in[1];
    const float* w1hh = (const float*)d_in[2];
    const float* b1i = (const float*)d_in[3];
    const float* b1h = (const float*)d_in[4];
    const float* w2ih = (const float*)d_in[5];
    const float* w2hh = (const float*)d_in[6];
    const float* b2i = (const float*)d_in[7];
    const float* b2h = (const float*)d_in[8];
    const float* w3ih = (const float*)d_in[9];
    const float* w3hh = (const float*)d_in[10];
    const float* b3i = (const float*)d_in[11];
    const float* b3h = (const float*)d_in[12];
    const float* w4ih = (const float*)d_in[13];
    const float* w4hh = (const float*)d_in[14];
    const float* b4i = (const float*)d_in[15];
    const float* b4h = (const float*)d_in[16];
    float* out = (float*)d_out;

    lstm_ae<<<dim3(BATCH / BPB), dim3(BLOCK), SMEM_BYTES, stream>>>(
        xi, w1ih, w1hh, b1i, b1h, w2ih, w2hh, b2i, b2h,
        w3ih, w3hh, b3i, b3h, w4ih, w4hh, b4i, b4h, out);
}

// Round 6
// 575.118 us; speedup vs baseline: 3.2070x; 2.8802x over previous
//
#include <hip/hip_runtime.h>
#include <stdint.h>

// LSTM autoencoder B=32768 T=30 I=4 H=64 L=32, fp32 in/out.
// v6: MFMA rewrite. Wave = 16 batches (M=16). bf16 hi/lo 3-term split
// (w_hi*h_hi + w_lo*h_hi + w_hi*h_lo) for ~2^-17 effective precision.
// Verified layouts: C/D col=lane&15,row=(lane>>4)*4+reg [m89];
// A m=lane&15,k=(lane>>4)*8+j [m120]; B n=lane&15,k=(lane>>4)*8+j.
// Weights staged to LDS in B-fragment order (1 ds_read_b128 per frag),
// two phases (enc, then dec re-staged). K=4 matmuls (Wih1*x, Whh4*h4)
// stay exact fp32 VALU. Wih3*latent hoisted out of the dec t-loop.

typedef unsigned short u16;
typedef unsigned int u32;
typedef __attribute__((ext_vector_type(8))) short bf16x8;
typedef __attribute__((ext_vector_type(4))) float f32x4;

#define BATCH 32768
#define TT 30
#define IN 4
#define WAVES 4
#define BLOCKT (WAVES * 64)
#define MB 16
#define BPB (WAVES * MB)   // 64 batches/block

// ---- LDS word (u32/float) offsets ----
#define WREG 29696
// enc phase
#define O_WHH1HI 0
#define O_WHH1LO 8192
#define O_WIH2HI 16384
#define O_WIH2LO 20480
#define O_WHH2HI 24576
#define O_WHH2LO 26624
#define O_W1IHF  28672   // fp32 [256][4]
// dec phase (same region)
#define O_WHH3HI 0
#define O_WHH3LO 8192
#define O_WIH3HI 16384
#define O_WIH3LO 20480
#define O_WIH4HI 24576
#define O_WIH4LO 25088
#define O_W4HHF  25600   // fp32 [16][4]

#define NBIAS 656
#define BUFW 1856   // floats per wave: h1hi 512|h1lo 512|h2hi 256|h2lo 256|gbuf 256|h4 64
#define SMEM_WORDS (WREG + NBIAS + WAVES * BUFW)
#define SMEM_BYTES (SMEM_WORDS * 4)   // 151104 <= 163840

#define WB() __builtin_amdgcn_wave_barrier()
#define MFMA(a, b, c) __builtin_amdgcn_mfma_f32_16x16x32_bf16((a), (b), (c), 0, 0, 0)

__device__ __forceinline__ u16 f2bf(float f) {   // RNE fp32->bf16
    u32 u = __float_as_uint(f);
    u += 0x7fffu + ((u >> 16) & 1u);
    return (u16)(u >> 16);
}
__device__ __forceinline__ float bf2f(u16 v) { return __uint_as_float(((u32)v) << 16); }
__device__ __forceinline__ float sigf(float x) {
    return __builtin_amdgcn_rcpf(1.f + __expf(-x));
}
__device__ __forceinline__ float tanh_(float x) {
    const float t = __expf(2.f * x);
    return fmaf(-2.f, __builtin_amdgcn_rcpf(t + 1.f), 1.f);
}

// Stage fp32 W[N][K] (row-major) -> bf16 hi/lo arrays in B-fragment order:
// u16 idx = ((nt*KT + kt)*64 + l)*8 + j, where n = nt*16 + (l&15),
// k = kt*32 + ((l>>4)<<3) + j.   (KT = K/32, power of 2)
template <int KT>
__device__ __forceinline__ void stageB(u16* hi, u16* lo, const float* src,
                                       int N, int tid) {
    const int K = KT * 32;
    const int total = N * K;
    for (int idx = tid; idx < total; idx += BLOCKT) {
        const int j = idx & 7;
        const int l = (idx >> 3) & 63;
        const int pair = idx >> 9;
        const int kt = pair & (KT - 1);
        const int nt = pair / KT;
        const int n = (nt << 4) | (l & 15);
        const int k = (kt << 5) + ((l >> 4) << 3) + j;
        const float w = src[n * K + k];
        const u16 h = f2bf(w);
        hi[idx] = h;
        lo[idx] = f2bf(w - bf2f(h));
    }
}

// write h into A-fragment layout (64- or 32-unit layers):
// element (m, u): kt=u>>5, l'=(m&15)+(((u>>3)&3)<<4), j=u&7
__device__ __forceinline__ void writeA(u16* Ahi, u16* Alo, int idx, float h) {
    const u16 hb = f2bf(h);
    Ahi[idx] = hb;
    Alo[idx] = f2bf(h - bf2f(hb));
}

__device__ __forceinline__ f32x4 splat4(float b) {
    f32x4 v = {b, b, b, b};
    return v;
}

__global__ __launch_bounds__(BLOCKT, 1) void lstm_ae(
    const float* __restrict__ x,
    const float* __restrict__ w1ih, const float* __restrict__ w1hh,
    const float* __restrict__ b1i, const float* __restrict__ b1h,
    const float* __restrict__ w2ih, const float* __restrict__ w2hh,
    const float* __restrict__ b2i, const float* __restrict__ b2h,
    const float* __restrict__ w3ih, const float* __restrict__ w3hh,
    const float* __restrict__ b3i, const float* __restrict__ b3h,
    const float* __restrict__ w4ih, const float* __restrict__ w4hh,
    const float* __restrict__ b4i, const float* __restrict__ b4h,
    float* __restrict__ out) {
    extern __shared__ float smem[];
    float* W = smem;
    float* biasF = smem + WREG;        // b1[256] b2[128] b3[256] b4[16]
    float* bufs = biasF + NBIAS;

    const int tid = threadIdx.x;
    const int wave = tid >> 6, lane = tid & 63;
    const int col = lane & 15, quad = lane >> 4;

    float* wbuf = bufs + wave * BUFW;
    u16* h1hi = (u16*)(wbuf);          // 1024 u16 (h1/h3, A-layout, 2 k-tiles)
    u16* h1lo = (u16*)(wbuf + 512);
    u16* h2hi = (u16*)(wbuf + 1024);   // 512 u16 (h2/latent, 1 k-tile)
    u16* h2lo = (u16*)(wbuf + 1280);
    float* gbuf = wbuf + 1536;         // [16 batch][16 gate] fp32
    float* bufH4 = wbuf + 1792;        // [16 batch][4] fp32

    const int b0w = blockIdx.x * BPB + wave * MB;

    // ---------------- stage ENCODER weights + biases ----------------
    stageB<2>((u16*)(W + O_WHH1HI), (u16*)(W + O_WHH1LO), w1hh, 256, tid);
    stageB<2>((u16*)(W + O_WIH2HI), (u16*)(W + O_WIH2LO), w2ih, 128, tid);
    stageB<1>((u16*)(W + O_WHH2HI), (u16*)(W + O_WHH2LO), w2hh, 128, tid);
    for (int i = tid; i < 1024; i += BLOCKT) W[O_W1IHF + i] = w1ih[i];
    for (int i = tid; i < 256; i += BLOCKT) biasF[i] = b1i[i] + b1h[i];
    for (int i = tid; i < 128; i += BLOCKT) biasF[256 + i] = b2i[i] + b2h[i];
    for (int i = tid; i < 256; i += BLOCKT) biasF[384 + i] = b3i[i] + b3h[i];
    for (int i = tid; i < 16; i += BLOCKT) biasF[640 + i] = b4i[i] + b4h[i];
    // zero h1/h2 A-buffers (wave-private region: 1536 u32 words)
    {
        u32* z = (u32*)wbuf;
        for (int i = lane; i < 1536; i += 64) z[i] = 0u;
    }
    __syncthreads();

    // per-lane biases (col-indexed)
    float bias1r[16], bias2r[8], bias3r[16];
#pragma unroll
    for (int nt = 0; nt < 16; ++nt) bias1r[nt] = biasF[nt * 16 + col];
#pragma unroll
    for (int nt = 0; nt < 8; ++nt) bias2r[nt] = biasF[256 + nt * 16 + col];
#pragma unroll
    for (int nt = 0; nt < 16; ++nt) bias3r[nt] = biasF[384 + nt * 16 + col];
    const float bias4r = biasF[640 + col];

    const u16* Whh1hi = (const u16*)(W + O_WHH1HI);
    const u16* Whh1lo = (const u16*)(W + O_WHH1LO);
    const u16* Wih2hi = (const u16*)(W + O_WIH2HI);
    const u16* Wih2lo = (const u16*)(W + O_WIH2LO);
    const u16* Whh2hi = (const u16*)(W + O_WHH2HI);
    const u16* Whh2lo = (const u16*)(W + O_WHH2LO);
    const float* W1ihF = W + O_W1IHF;

    // ================= encoder =================
    float c1[4][4], c2[2][4];
#pragma unroll
    for (int q = 0; q < 4; ++q)
#pragma unroll
        for (int r = 0; r < 4; ++r) c1[q][r] = 0.f;
#pragma unroll
    for (int q = 0; q < 2; ++q)
#pragma unroll
        for (int r = 0; r < 4; ++r) c2[q][r] = 0.f;

    for (int t = 0; t < TT; ++t) {
        // x for this wave's rows (issued early; used after the MFMA block)
        float4 xv[4];
#pragma unroll
        for (int r = 0; r < 4; ++r)
            xv[r] = *reinterpret_cast<const float4*>(
                x + ((size_t)(b0w + quad * 4 + r) * TT + t) * IN);

        // ---- enc1: gates1 = b1 + Whh1*h1[t-1] (MFMA) + Wih1*x (VALU) ----
        bf16x8 a1h0 = *reinterpret_cast<const bf16x8*>(h1hi + lane * 8);
        bf16x8 a1h1 = *reinterpret_cast<const bf16x8*>(h1hi + (64 + lane) * 8);
        bf16x8 a1l0 = *reinterpret_cast<const bf16x8*>(h1lo + lane * 8);
        bf16x8 a1l1 = *reinterpret_cast<const bf16x8*>(h1lo + (64 + lane) * 8);
        f32x4 acc1[16];
#pragma unroll
        for (int nt = 0; nt < 16; ++nt) acc1[nt] = splat4(bias1r[nt]);
#pragma unroll
        for (int nt = 0; nt < 16; ++nt) {
            const bf16x8 bh0 = *reinterpret_cast<const bf16x8*>(Whh1hi + ((nt * 2 + 0) * 64 + lane) * 8);
            const bf16x8 bl0 = *reinterpret_cast<const bf16x8*>(Whh1lo + ((nt * 2 + 0) * 64 + lane) * 8);
            const bf16x8 bh1 = *reinterpret_cast<const bf16x8*>(Whh1hi + ((nt * 2 + 1) * 64 + lane) * 8);
            const bf16x8 bl1 = *reinterpret_cast<const bf16x8*>(Whh1lo + ((nt * 2 + 1) * 64 + lane) * 8);
            acc1[nt] = MFMA(a1h0, bh0, acc1[nt]);
            acc1[nt] = MFMA(a1l0, bh0, acc1[nt]);
            acc1[nt] = MFMA(a1h0, bl0, acc1[nt]);
            acc1[nt] = MFMA(a1h1, bh1, acc1[nt]);
            acc1[nt] = MFMA(a1l1, bh1, acc1[nt]);
            acc1[nt] = MFMA(a1h1, bl1, acc1[nt]);
        }
        // exact fp32 x-contribution
#pragma unroll
        for (int nt = 0; nt < 16; ++nt) {
            const float4 w = *reinterpret_cast<const float4*>(W1ihF + (nt * 16 + col) * 4);
#pragma unroll
            for (int r = 0; r < 4; ++r) {
                float s = acc1[nt][r];
                s = fmaf(w.x, xv[r].x, s);
                s = fmaf(w.y, xv[r].y, s);
                s = fmaf(w.z, xv[r].z, s);
                s = fmaf(w.w, xv[r].w, s);
                acc1[nt][r] = s;
            }
        }
        // activations; write h1[t] into A-layout (u = q*16+col, m = quad*4+r)
        WB();
#pragma unroll
        for (int q = 0; q < 4; ++q) {
            const int kt = q >> 1;
            const int lup = ((((q & 1) << 1) + (col >> 3)) << 4);
            const int j = col & 7;
#pragma unroll
            for (int r = 0; r < 4; ++r) {
                const int m = quad * 4 + r;
                const float iv = sigf(acc1[q][r]);
                const float fv = sigf(acc1[4 + q][r]);
                const float gv = tanh_(acc1[8 + q][r]);
                const float ov = sigf(acc1[12 + q][r]);
                c1[q][r] = fv * c1[q][r] + iv * gv;
                const float h = ov * tanh_(c1[q][r]);
                writeA(h1hi, h1lo, (kt * 64 + m + lup) * 8 + j, h);
            }
        }
        WB();
        // ---- enc2: gates2 = b2 + Wih2*h1[t] + Whh2*h2[t-1] ----
        a1h0 = *reinterpret_cast<const bf16x8*>(h1hi + lane * 8);
        a1h1 = *reinterpret_cast<const bf16x8*>(h1hi + (64 + lane) * 8);
        a1l0 = *reinterpret_cast<const bf16x8*>(h1lo + lane * 8);
        a1l1 = *reinterpret_cast<const bf16x8*>(h1lo + (64 + lane) * 8);
        const bf16x8 a2h = *reinterpret_cast<const bf16x8*>(h2hi + lane * 8);
        const bf16x8 a2l = *reinterpret_cast<const bf16x8*>(h2lo + lane * 8);
        f32x4 acc2[8];
#pragma unroll
        for (int nt = 0; nt < 8; ++nt) acc2[nt] = splat4(bias2r[nt]);
#pragma unroll
        for (int nt = 0; nt < 8; ++nt) {
            const bf16x8 bh0 = *reinterpret_cast<const bf16x8*>(Wih2hi + ((nt * 2 + 0) * 64 + lane) * 8);
            const bf16x8 bl0 = *reinterpret_cast<const bf16x8*>(Wih2lo + ((nt * 2 + 0) * 64 + lane) * 8);
            const bf16x8 bh1 = *reinterpret_cast<const bf16x8*>(Wih2hi + ((nt * 2 + 1) * 64 + lane) * 8);
            const bf16x8 bl1 = *reinterpret_cast<const bf16x8*>(Wih2lo + ((nt * 2 + 1) * 64 + lane) * 8);
            const bf16x8 ch = *reinterpret_cast<const bf16x8*>(Whh2hi + (nt * 64 + lane) * 8);
            const bf16x8 cl = *reinterpret_cast<const bf16x8*>(Whh2lo + (nt * 64 + lane) * 8);
            acc2[nt] = MFMA(a1h0, bh0, acc2[nt]);
            acc2[nt] = MFMA(a1l0, bh0, acc2[nt]);
            acc2[nt] = MFMA(a1h0, bl0, acc2[nt]);
            acc2[nt] = MFMA(a1h1, bh1, acc2[nt]);
            acc2[nt] = MFMA(a1l1, bh1, acc2[nt]);
            acc2[nt] = MFMA(a1h1, bl1, acc2[nt]);
            acc2[nt] = MFMA(a2h, ch, acc2[nt]);
            acc2[nt] = MFMA(a2l, ch, acc2[nt]);
            acc2[nt] = MFMA(a2h, cl, acc2[nt]);
        }
        WB();
#pragma unroll
        for (int q = 0; q < 2; ++q) {   // u = q*16+col, kt=0
            const int lup = (((q << 1) + (col >> 3)) << 4);
            const int j = col & 7;
#pragma unroll
            for (int r = 0; r < 4; ++r) {
                const int m = quad * 4 + r;
                const float iv = sigf(acc2[q][r]);
                const float fv = sigf(acc2[2 + q][r]);
                const float gv = tanh_(acc2[4 + q][r]);
                const float ov = sigf(acc2[6 + q][r]);
                c2[q][r] = fv * c2[q][r] + iv * gv;
                const float h = ov * tanh_(c2[q][r]);
                writeA(h2hi, h2lo, (m + lup) * 8 + j, h);
            }
        }
        WB();
    }
    // h2 buffers now hold the latent (read-only below).

    __syncthreads();   // all waves done with encoder weights

    // ---------------- re-stage DECODER weights ----------------
    stageB<2>((u16*)(W + O_WHH3HI), (u16*)(W + O_WHH3LO), w3hh, 256, tid);
    stageB<1>((u16*)(W + O_WIH3HI), (u16*)(W + O_WIH3LO), w3ih, 256, tid);
    stageB<2>((u16*)(W + O_WIH4HI), (u16*)(W + O_WIH4LO), w4ih, 16, tid);
    for (int i = tid; i < 64; i += BLOCKT) W[O_W4HHF + i] = w4hh[i];
    // zero h3 (h1 slot) + h4 state
    {
        u32* z = (u32*)wbuf;
        for (int i = lane; i < 1024; i += 64) z[i] = 0u;
        if (lane < 64) bufH4[lane] = 0.f;
    }
    __syncthreads();

    const u16* Whh3hi = (const u16*)(W + O_WHH3HI);
    const u16* Whh3lo = (const u16*)(W + O_WHH3LO);
    const u16* Wih3hi = (const u16*)(W + O_WIH3HI);
    const u16* Wih3lo = (const u16*)(W + O_WIH3LO);
    const u16* Wih4hi = (const u16*)(W + O_WIH4HI);
    const u16* Wih4lo = (const u16*)(W + O_WIH4LO);
    const float* W4hhF = W + O_W4HHF;

    // preactL = b3 + Wih3 * latent (constant over t)
    f32x4 preactL[16];
    {
        const bf16x8 aLh = *reinterpret_cast<const bf16x8*>(h2hi + lane * 8);
        const bf16x8 aLl = *reinterpret_cast<const bf16x8*>(h2lo + lane * 8);
#pragma unroll
        for (int nt = 0; nt < 16; ++nt) {
            f32x4 a = splat4(bias3r[nt]);
            const bf16x8 bh = *reinterpret_cast<const bf16x8*>(Wih3hi + (nt * 64 + lane) * 8);
            const bf16x8 bl = *reinterpret_cast<const bf16x8*>(Wih3lo + (nt * 64 + lane) * 8);
            a = MFMA(aLh, bh, a);
            a = MFMA(aLl, bh, a);
            a = MFMA(aLh, bl, a);
            preactL[nt] = a;
        }
    }

    float c3[4][4], c4 = 0.f;
#pragma unroll
    for (int q = 0; q < 4; ++q)
#pragma unroll
        for (int r = 0; r < 4; ++r) c3[q][r] = 0.f;
    const int u4 = lane & 3, mb = lane >> 2;   // dec2 epilogue task (all 64 lanes)

    for (int t = 0; t < TT; ++t) {
        // ---- dec1: gates3 = preactL + Whh3*h3[t-1] ----
        bf16x8 a3h0 = *reinterpret_cast<const bf16x8*>(h1hi + lane * 8);
        bf16x8 a3h1 = *reinterpret_cast<const bf16x8*>(h1hi + (64 + lane) * 8);
        bf16x8 a3l0 = *reinterpret_cast<const bf16x8*>(h1lo + lane * 8);
        bf16x8 a3l1 = *reinterpret_cast<const bf16x8*>(h1lo + (64 + lane) * 8);
        f32x4 acc3[16];
#pragma unroll
        for (int nt = 0; nt < 16; ++nt) acc3[nt] = preactL[nt];
#pragma unroll
        for (int nt = 0; nt < 16; ++nt) {
            const bf16x8 bh0 = *reinterpret_cast<const bf16x8*>(Whh3hi + ((nt * 2 + 0) * 64 + lane) * 8);
            const bf16x8 bl0 = *reinterpret_cast<const bf16x8*>(Whh3lo + ((nt * 2 + 0) * 64 + lane) * 8);
            const bf16x8 bh1 = *reinterpret_cast<const bf16x8*>(Whh3hi + ((nt * 2 + 1) * 64 + lane) * 8);
            const bf16x8 bl1 = *reinterpret_cast<const bf16x8*>(Whh3lo + ((nt * 2 + 1) * 64 + lane) * 8);
            acc3[nt] = MFMA(a3h0, bh0, acc3[nt]);
            acc3[nt] = MFMA(a3l0, bh0, acc3[nt]);
            acc3[nt] = MFMA(a3h0, bl0, acc3[nt]);
            acc3[nt] = MFMA(a3h1, bh1, acc3[nt]);
            acc3[nt] = MFMA(a3l1, bh1, acc3[nt]);
            acc3[nt] = MFMA(a3h1, bl1, acc3[nt]);
        }
        WB();
#pragma unroll
        for (int q = 0; q < 4; ++q) {
            const int kt = q >> 1;
            const int lup = ((((q & 1) << 1) + (col >> 3)) << 4);
            const int j = col & 7;
#pragma unroll
            for (int r = 0; r < 4; ++r) {
                const int m = quad * 4 + r;
                const float iv = sigf(acc3[q][r]);
                const float fv = sigf(acc3[4 + q][r]);
                const float gv = tanh_(acc3[8 + q][r]);
                const float ov = sigf(acc3[12 + q][r]);
                c3[q][r] = fv * c3[q][r] + iv * gv;
                const float h = ov * tanh_(c3[q][r]);
                writeA(h1hi, h1lo, (kt * 64 + m + lup) * 8 + j, h);
            }
        }
        WB();
        // ---- dec2: gates4 = b4 + Whh4*h4[t-1] (VALU) + Wih4*h3[t] (MFMA) ----
        a3h0 = *reinterpret_cast<const bf16x8*>(h1hi + lane * 8);
        a3h1 = *reinterpret_cast<const bf16x8*>(h1hi + (64 + lane) * 8);
        a3l0 = *reinterpret_cast<const bf16x8*>(h1lo + lane * 8);
        a3l1 = *reinterpret_cast<const bf16x8*>(h1lo + (64 + lane) * 8);
        f32x4 acc4 = splat4(bias4r);
        {
            const float4 w4 = *reinterpret_cast<const float4*>(W4hhF + col * 4);
#pragma unroll
            for (int r = 0; r < 4; ++r) {
                const float4 hv = *reinterpret_cast<const float4*>(bufH4 + (quad * 4 + r) * 4);
                float s = acc4[r];
                s = fmaf(w4.x, hv.x, s);
                s = fmaf(w4.y, hv.y, s);
                s = fmaf(w4.z, hv.z, s);
                s = fmaf(w4.w, hv.w, s);
                acc4[r] = s;
            }
        }
        {
            const bf16x8 bh0 = *reinterpret_cast<const bf16x8*>(Wih4hi + (0 * 64 + lane) * 8);
            const bf16x8 bl0 = *reinterpret_cast<const bf16x8*>(Wih4lo + (0 * 64 + lane) * 8);
            const bf16x8 bh1 = *reinterpret_cast<const bf16x8*>(Wih4hi + (1 * 64 + lane) * 8);
            const bf16x8 bl1 = *reinterpret_cast<const bf16x8*>(Wih4lo + (1 * 64 + lane) * 8);
            acc4 = MFMA(a3h0, bh0, acc4);
            acc4 = MFMA(a3l0, bh0, acc4);
            acc4 = MFMA(a3h0, bl0, acc4);
            acc4 = MFMA(a3h1, bh1, acc4);
            acc4 = MFMA(a3l1, bh1, acc4);
            acc4 = MFMA(a3h1, bl1, acc4);
        }
        WB();
#pragma unroll
        for (int r = 0; r < 4; ++r) gbuf[(quad * 4 + r) * 16 + col] = acc4[r];
        WB();
        // epilogue: lane = (batch mb, unit u4); no divergence
        {
            const float iv = sigf(gbuf[mb * 16 + u4]);
            const float fv = sigf(gbuf[mb * 16 + 4 + u4]);
            const float gv = tanh_(gbuf[mb * 16 + 8 + u4]);
            const float ov = sigf(gbuf[mb * 16 + 12 + u4]);
            c4 = fv * c4 + iv * gv;
            const float h = ov * tanh_(c4);
            out[((size_t)(b0w + mb) * TT + t) * IN + u4] = h;
            bufH4[mb * 4 + u4] = h;
        }
        WB();
    }
}

extern "C" void kernel_launch(void* const* d_in, const int* in_sizes, int n_in,
                              void* d_out, int out_size, void* d_ws, size_t ws_size,
                              hipStream_t stream) {
    (void)in_sizes; (void)n_in; (void)d_ws; (void)ws_size; (void)out_size;
    hipFuncSetAttribute(reinterpret_cast<const void*>(lstm_ae),
                        hipFuncAttributeMaxDynamicSharedMemorySize, SMEM_BYTES);
    const float* xi = (const float*)d_in[0];
    const float* w1ih = (const float*)d_in[1];
    const float* w1hh = (const float*)d_in[2];
    const float* b1i = (const float*)d_in[3];
    const float* b1h = (const float*)d_in[4];
    const float* w2ih = (const float*)d_in[5];
    const float* w2hh = (const float*)d_in[6];
    const float* b2i = (const float*)d_in[7];
    const float* b2h = (const float*)d_in[8];
    const float* w3ih = (const float*)d_in[9];
    const float* w3hh = (const float*)d_in[10];
    const float* b3i = (const float*)d_in[11];
    const float* b3h = (const float*)d_in[12];
    const float* w4ih = (const float*)d_in[13];
    const float* w4hh = (const float*)d_in[14];
    const float* b4i = (const float*)d_in[15];
    const float* b4h = (const float*)d_in[16];
    float* out = (float*)d_out;

    lstm_ae<<<dim3(BATCH / BPB), dim3(BLOCKT), SMEM_BYTES, stream>>>(
        xi, w1ih, w1hh, b1i, b1h, w2ih, w2hh, b2i, b2h,
        w3ih, w3hh, b3i, b3h, w4ih, w4hh, b4i, b4h, out);
}

// Round 8
// 446.111 us; speedup vs baseline: 4.1344x; 1.2892x over previous
//
#include <hip/hip_runtime.h>
#include <stdint.h>

// LSTM autoencoder B=32768 T=30 I=4 H=64 L=32, fp32 in/out.
// v8 = v7 with the decoder LDS-offset bug fixed (Wih4hi is 512 words, not
// 256: W4HHF moved past it and WREG grown to 25152; v7 had W4hh staging
// overwrite Wih4hi -> saturated garbage).
// Structure: 8 waves/block (512 thr), BPB=128, grid=256 -> 1 block/CU,
// 2 waves/SIMD, single dispatch round. Small weight mats (Wih2, Whh2, Wih4)
// 2-term (w bf16 hi only); recurrent mats (Whh1, Whh3, Wih3) 3-term.
// Verified layouts: C/D col=lane&15,row=(lane>>4)*4+reg [m89];
// A m=lane&15,k=(lane>>4)*8+j [m120]; B n=lane&15,k=(lane>>4)*8+j.

typedef unsigned short u16;
typedef unsigned int u32;
typedef __attribute__((ext_vector_type(8))) short bf16x8;
typedef __attribute__((ext_vector_type(4))) float f32x4;

#define BATCH 32768
#define TT 30
#define IN 4
#define WAVES 8
#define BLOCKT (WAVES * 64)   // 512
#define MB 16
#define BPB (WAVES * MB)      // 128 batches/block -> grid 256, 1 round

// ---- LDS word (u32/float) offsets ----
#define WREG 25152
// enc phase
#define O_WHH1HI 0       // 8192 words (16384 u16)
#define O_WHH1LO 8192    // 8192
#define O_WIH2HI 16384   // 4096 (hi only)
#define O_WHH2HI 20480   // 2048 (hi only)
#define O_W1IHF  22528   // 1024 fp32
// dec phase (same region)
#define O_WHH3HI 0       // 8192
#define O_WHH3LO 8192    // 8192
#define O_WIH3HI 16384   // 4096
#define O_WIH3LO 20480   // 4096
#define O_WIH4HI 24576   // 512 words (1024 u16, hi only)
#define O_W4HHF  25088   // 64 fp32  -> ends 25152 == WREG

#define NBIAS 656
#define BUFW 1856   // per-wave floats: h1hi 512|h1lo 512|h2hi 256|h2lo 256|gbuf 256|h4 64
#define SMEM_WORDS (WREG + NBIAS + WAVES * BUFW)   // 40656
#define SMEM_BYTES (SMEM_WORDS * 4)                // 162624 <= 163840

#define WB() __builtin_amdgcn_wave_barrier()
#define MFMA(a, b, c) __builtin_amdgcn_mfma_f32_16x16x32_bf16((a), (b), (c), 0, 0, 0)

__device__ __forceinline__ u16 f2bf(float f) {   // RNE fp32->bf16
    u32 u = __float_as_uint(f);
    u += 0x7fffu + ((u >> 16) & 1u);
    return (u16)(u >> 16);
}
__device__ __forceinline__ float bf2f(u16 v) { return __uint_as_float(((u32)v) << 16); }
__device__ __forceinline__ float sigf(float x) {
    return __builtin_amdgcn_rcpf(1.f + __expf(-x));
}
__device__ __forceinline__ float tanh_(float x) {
    const float t = __expf(2.f * x);
    return fmaf(-2.f, __builtin_amdgcn_rcpf(t + 1.f), 1.f);
}

// Stage fp32 W[N][K] -> bf16 hi+lo, B-fragment order:
// u16 idx = ((nt*KT + kt)*64 + l)*8 + j, n = nt*16+(l&15), k = kt*32+((l>>4)<<3)+j
template <int KT>
__device__ __forceinline__ void stageB(u16* hi, u16* lo, const float* src,
                                       int N, int tid) {
    const int K = KT * 32;
    const int total = N * K;
    for (int idx = tid; idx < total; idx += BLOCKT) {
        const int j = idx & 7;
        const int l = (idx >> 3) & 63;
        const int pair = idx >> 9;
        const int kt = pair & (KT - 1);
        const int nt = pair / KT;
        const int n = (nt << 4) | (l & 15);
        const int k = (kt << 5) + ((l >> 4) << 3) + j;
        const float w = src[n * K + k];
        const u16 h = f2bf(w);
        hi[idx] = h;
        lo[idx] = f2bf(w - bf2f(h));
    }
}
// hi-only variant (2-term weights)
template <int KT>
__device__ __forceinline__ void stageBh(u16* hi, const float* src, int N, int tid) {
    const int K = KT * 32;
    const int total = N * K;
    for (int idx = tid; idx < total; idx += BLOCKT) {
        const int j = idx & 7;
        const int l = (idx >> 3) & 63;
        const int pair = idx >> 9;
        const int kt = pair & (KT - 1);
        const int nt = pair / KT;
        const int n = (nt << 4) | (l & 15);
        const int k = (kt << 5) + ((l >> 4) << 3) + j;
        hi[idx] = f2bf(src[n * K + k]);
    }
}

// write h into A-fragment layout: element (m,u): kt=u>>5, lup=16*((u>>3)&3), j=u&7
__device__ __forceinline__ void writeA(u16* Ahi, u16* Alo, int idx, float h) {
    const u16 hb = f2bf(h);
    Ahi[idx] = hb;
    Alo[idx] = f2bf(h - bf2f(hb));
}

__device__ __forceinline__ f32x4 splat4(float b) {
    f32x4 v = {b, b, b, b};
    return v;
}

__global__ __launch_bounds__(BLOCKT, 2) void lstm_ae(
    const float* __restrict__ x,
    const float* __restrict__ w1ih, const float* __restrict__ w1hh,
    const float* __restrict__ b1i, const float* __restrict__ b1h,
    const float* __restrict__ w2ih, const float* __restrict__ w2hh,
    const float* __restrict__ b2i, const float* __restrict__ b2h,
    const float* __restrict__ w3ih, const float* __restrict__ w3hh,
    const float* __restrict__ b3i, const float* __restrict__ b3h,
    const float* __restrict__ w4ih, const float* __restrict__ w4hh,
    const float* __restrict__ b4i, const float* __restrict__ b4h,
    float* __restrict__ out) {
    extern __shared__ float smem[];
    float* W = smem;
    float* biasF = smem + WREG;        // b1[256] b2[128] b3[256] b4[16]
    float* bufs = biasF + NBIAS;

    const int tid = threadIdx.x;
    const int wave = tid >> 6, lane = tid & 63;
    const int col = lane & 15, quad = lane >> 4;

    float* wbuf = bufs + wave * BUFW;
    u16* h1hi = (u16*)(wbuf);          // 1024 u16 (h1/h3, A-layout, 2 k-tiles)
    u16* h1lo = (u16*)(wbuf + 512);
    u16* h2hi = (u16*)(wbuf + 1024);   // 512 u16 (h2/latent, 1 k-tile)
    u16* h2lo = (u16*)(wbuf + 1280);
    float* gbuf = wbuf + 1536;         // [16 batch][16 gate] fp32 (dec only)
    float* bufH4 = wbuf + 1792;        // [16 batch][4] fp32 (dec only)

    const int b0w = blockIdx.x * BPB + wave * MB;

    // ---------------- stage ENCODER weights + biases ----------------
    stageB<2>((u16*)(W + O_WHH1HI), (u16*)(W + O_WHH1LO), w1hh, 256, tid);
    stageBh<2>((u16*)(W + O_WIH2HI), w2ih, 128, tid);
    stageBh<1>((u16*)(W + O_WHH2HI), w2hh, 128, tid);
    for (int i = tid; i < 1024; i += BLOCKT) W[O_W1IHF + i] = w1ih[i];
    for (int i = tid; i < 256; i += BLOCKT) biasF[i] = b1i[i] + b1h[i];
    for (int i = tid; i < 128; i += BLOCKT) biasF[256 + i] = b2i[i] + b2h[i];
    for (int i = tid; i < 256; i += BLOCKT) biasF[384 + i] = b3i[i] + b3h[i];
    for (int i = tid; i < 16; i += BLOCKT) biasF[640 + i] = b4i[i] + b4h[i];
    // zero h1/h2 A-buffers (wave-private, 1536 words)
    {
        u32* z = (u32*)wbuf;
        for (int i = lane; i < 1536; i += 64) z[i] = 0u;
    }
    __syncthreads();

    // small per-lane biases kept in regs; large ones re-read from LDS
    float bias2r[8];
#pragma unroll
    for (int nt = 0; nt < 8; ++nt) bias2r[nt] = biasF[256 + nt * 16 + col];
    const float bias4r = biasF[640 + col];

    const u16* Whh1hi = (const u16*)(W + O_WHH1HI);
    const u16* Whh1lo = (const u16*)(W + O_WHH1LO);
    const u16* Wih2hi = (const u16*)(W + O_WIH2HI);
    const u16* Whh2hi = (const u16*)(W + O_WHH2HI);
    const float* W1ihF = W + O_W1IHF;

    // ================= encoder =================
    float c1[4][4], c2[2][4];
#pragma unroll
    for (int q = 0; q < 4; ++q)
#pragma unroll
        for (int r = 0; r < 4; ++r) c1[q][r] = 0.f;
#pragma unroll
    for (int q = 0; q < 2; ++q)
#pragma unroll
        for (int r = 0; r < 4; ++r) c2[q][r] = 0.f;

    for (int t = 0; t < TT; ++t) {
        float4 xv[4];
#pragma unroll
        for (int r = 0; r < 4; ++r)
            xv[r] = *reinterpret_cast<const float4*>(
                x + ((size_t)(b0w + quad * 4 + r) * TT + t) * IN);

        // ---- enc1: gates1 = b1 + Whh1*h1[t-1] (MFMA 3-term) + Wih1*x (VALU) ----
        bf16x8 a1h0 = *reinterpret_cast<const bf16x8*>(h1hi + lane * 8);
        bf16x8 a1h1 = *reinterpret_cast<const bf16x8*>(h1hi + (64 + lane) * 8);
        bf16x8 a1l0 = *reinterpret_cast<const bf16x8*>(h1lo + lane * 8);
        bf16x8 a1l1 = *reinterpret_cast<const bf16x8*>(h1lo + (64 + lane) * 8);
        f32x4 acc1[16];
#pragma unroll
        for (int nt = 0; nt < 16; ++nt) acc1[nt] = splat4(biasF[nt * 16 + col]);
#pragma unroll
        for (int nt = 0; nt < 16; ++nt) {
            const bf16x8 bh0 = *reinterpret_cast<const bf16x8*>(Whh1hi + ((nt * 2 + 0) * 64 + lane) * 8);
            const bf16x8 bl0 = *reinterpret_cast<const bf16x8*>(Whh1lo + ((nt * 2 + 0) * 64 + lane) * 8);
            const bf16x8 bh1 = *reinterpret_cast<const bf16x8*>(Whh1hi + ((nt * 2 + 1) * 64 + lane) * 8);
            const bf16x8 bl1 = *reinterpret_cast<const bf16x8*>(Whh1lo + ((nt * 2 + 1) * 64 + lane) * 8);
            acc1[nt] = MFMA(a1h0, bh0, acc1[nt]);
            acc1[nt] = MFMA(a1l0, bh0, acc1[nt]);
            acc1[nt] = MFMA(a1h0, bl0, acc1[nt]);
            acc1[nt] = MFMA(a1h1, bh1, acc1[nt]);
            acc1[nt] = MFMA(a1l1, bh1, acc1[nt]);
            acc1[nt] = MFMA(a1h1, bl1, acc1[nt]);
        }
#pragma unroll
        for (int nt = 0; nt < 16; ++nt) {   // exact fp32 x-contribution
            const float4 w = *reinterpret_cast<const float4*>(W1ihF + (nt * 16 + col) * 4);
#pragma unroll
            for (int r = 0; r < 4; ++r) {
                float s = acc1[nt][r];
                s = fmaf(w.x, xv[r].x, s);
                s = fmaf(w.y, xv[r].y, s);
                s = fmaf(w.z, xv[r].z, s);
                s = fmaf(w.w, xv[r].w, s);
                acc1[nt][r] = s;
            }
        }
        WB();
#pragma unroll
        for (int q = 0; q < 4; ++q) {   // h1[t] -> A-layout
            const int kt = q >> 1;
            const int lup = ((((q & 1) << 1) + (col >> 3)) << 4);
            const int j = col & 7;
#pragma unroll
            for (int r = 0; r < 4; ++r) {
                const int m = quad * 4 + r;
                const float iv = sigf(acc1[q][r]);
                const float fv = sigf(acc1[4 + q][r]);
                const float gv = tanh_(acc1[8 + q][r]);
                const float ov = sigf(acc1[12 + q][r]);
                c1[q][r] = fv * c1[q][r] + iv * gv;
                const float h = ov * tanh_(c1[q][r]);
                writeA(h1hi, h1lo, (kt * 64 + m + lup) * 8 + j, h);
            }
        }
        WB();
        // ---- enc2: gates2 = b2 + Wih2*h1[t] (2-term) + Whh2*h2[t-1] (2-term) ----
        a1h0 = *reinterpret_cast<const bf16x8*>(h1hi + lane * 8);
        a1h1 = *reinterpret_cast<const bf16x8*>(h1hi + (64 + lane) * 8);
        a1l0 = *reinterpret_cast<const bf16x8*>(h1lo + lane * 8);
        a1l1 = *reinterpret_cast<const bf16x8*>(h1lo + (64 + lane) * 8);
        const bf16x8 a2h = *reinterpret_cast<const bf16x8*>(h2hi + lane * 8);
        const bf16x8 a2l = *reinterpret_cast<const bf16x8*>(h2lo + lane * 8);
        f32x4 acc2[8];
#pragma unroll
        for (int nt = 0; nt < 8; ++nt) acc2[nt] = splat4(bias2r[nt]);
#pragma unroll
        for (int nt = 0; nt < 8; ++nt) {
            const bf16x8 bh0 = *reinterpret_cast<const bf16x8*>(Wih2hi + ((nt * 2 + 0) * 64 + lane) * 8);
            const bf16x8 bh1 = *reinterpret_cast<const bf16x8*>(Wih2hi + ((nt * 2 + 1) * 64 + lane) * 8);
            const bf16x8 ch = *reinterpret_cast<const bf16x8*>(Whh2hi + (nt * 64 + lane) * 8);
            acc2[nt] = MFMA(a1h0, bh0, acc2[nt]);
            acc2[nt] = MFMA(a1l0, bh0, acc2[nt]);
            acc2[nt] = MFMA(a1h1, bh1, acc2[nt]);
            acc2[nt] = MFMA(a1l1, bh1, acc2[nt]);
            acc2[nt] = MFMA(a2h, ch, acc2[nt]);
            acc2[nt] = MFMA(a2l, ch, acc2[nt]);
        }
        WB();
#pragma unroll
        for (int q = 0; q < 2; ++q) {   // h2[t] -> A-layout (kt=0)
            const int lup = (((q << 1) + (col >> 3)) << 4);
            const int j = col & 7;
#pragma unroll
            for (int r = 0; r < 4; ++r) {
                const int m = quad * 4 + r;
                const float iv = sigf(acc2[q][r]);
                const float fv = sigf(acc2[2 + q][r]);
                const float gv = tanh_(acc2[4 + q][r]);
                const float ov = sigf(acc2[6 + q][r]);
                c2[q][r] = fv * c2[q][r] + iv * gv;
                const float h = ov * tanh_(c2[q][r]);
                writeA(h2hi, h2lo, (m + lup) * 8 + j, h);
            }
        }
        WB();
    }
    // h2 buffers now hold the latent (read-only below).

    __syncthreads();   // all waves done with encoder weights

    // ---------------- re-stage DECODER weights ----------------
    stageB<2>((u16*)(W + O_WHH3HI), (u16*)(W + O_WHH3LO), w3hh, 256, tid);
    stageB<1>((u16*)(W + O_WIH3HI), (u16*)(W + O_WIH3LO), w3ih, 256, tid);
    stageBh<2>((u16*)(W + O_WIH4HI), w4ih, 16, tid);
    for (int i = tid; i < 64; i += BLOCKT) W[O_W4HHF + i] = w4hh[i];
    // zero h3 (h1 slot) + h4 state
    {
        u32* z = (u32*)wbuf;
        for (int i = lane; i < 1024; i += 64) z[i] = 0u;
        if (lane < 64) bufH4[lane] = 0.f;
    }
    __syncthreads();

    const u16* Whh3hi = (const u16*)(W + O_WHH3HI);
    const u16* Whh3lo = (const u16*)(W + O_WHH3LO);
    const u16* Wih3hi = (const u16*)(W + O_WIH3HI);
    const u16* Wih3lo = (const u16*)(W + O_WIH3LO);
    const u16* Wih4hi = (const u16*)(W + O_WIH4HI);
    const float* W4hhF = W + O_W4HHF;

    // preactL = b3 + Wih3 * latent (constant over t, 3-term)
    f32x4 preactL[16];
    {
        const bf16x8 aLh = *reinterpret_cast<const bf16x8*>(h2hi + lane * 8);
        const bf16x8 aLl = *reinterpret_cast<const bf16x8*>(h2lo + lane * 8);
#pragma unroll
        for (int nt = 0; nt < 16; ++nt) {
            f32x4 a = splat4(biasF[384 + nt * 16 + col]);
            const bf16x8 bh = *reinterpret_cast<const bf16x8*>(Wih3hi + (nt * 64 + lane) * 8);
            const bf16x8 bl = *reinterpret_cast<const bf16x8*>(Wih3lo + (nt * 64 + lane) * 8);
            a = MFMA(aLh, bh, a);
            a = MFMA(aLl, bh, a);
            a = MFMA(aLh, bl, a);
            preactL[nt] = a;
        }
    }

    float c3[4][4], c4 = 0.f;
#pragma unroll
    for (int q = 0; q < 4; ++q)
#pragma unroll
        for (int r = 0; r < 4; ++r) c3[q][r] = 0.f;
    const int u4 = lane & 3, mb = lane >> 2;   // dec2 epilogue task

    for (int t = 0; t < TT; ++t) {
        // ---- dec1: gates3 = preactL + Whh3*h3[t-1] (3-term) ----
        bf16x8 a3h0 = *reinterpret_cast<const bf16x8*>(h1hi + lane * 8);
        bf16x8 a3h1 = *reinterpret_cast<const bf16x8*>(h1hi + (64 + lane) * 8);
        bf16x8 a3l0 = *reinterpret_cast<const bf16x8*>(h1lo + lane * 8);
        bf16x8 a3l1 = *reinterpret_cast<const bf16x8*>(h1lo + (64 + lane) * 8);
        f32x4 acc3[16];
#pragma unroll
        for (int nt = 0; nt < 16; ++nt) acc3[nt] = preactL[nt];
#pragma unroll
        for (int nt = 0; nt < 16; ++nt) {
            const bf16x8 bh0 = *reinterpret_cast<const bf16x8*>(Whh3hi + ((nt * 2 + 0) * 64 + lane) * 8);
            const bf16x8 bl0 = *reinterpret_cast<const bf16x8*>(Whh3lo + ((nt * 2 + 0) * 64 + lane) * 8);
            const bf16x8 bh1 = *reinterpret_cast<const bf16x8*>(Whh3hi + ((nt * 2 + 1) * 64 + lane) * 8);
            const bf16x8 bl1 = *reinterpret_cast<const bf16x8*>(Whh3lo + ((nt * 2 + 1) * 64 + lane) * 8);
            acc3[nt] = MFMA(a3h0, bh0, acc3[nt]);
            acc3[nt] = MFMA(a3l0, bh0, acc3[nt]);
            acc3[nt] = MFMA(a3h0, bl0, acc3[nt]);
            acc3[nt] = MFMA(a3h1, bh1, acc3[nt]);
            acc3[nt] = MFMA(a3l1, bh1, acc3[nt]);
            acc3[nt] = MFMA(a3h1, bl1, acc3[nt]);
        }
        WB();
#pragma unroll
        for (int q = 0; q < 4; ++q) {   // h3[t] -> A-layout
            const int kt = q >> 1;
            const int lup = ((((q & 1) << 1) + (col >> 3)) << 4);
            const int j = col & 7;
#pragma unroll
            for (int r = 0; r < 4; ++r) {
                const int m = quad * 4 + r;
                const float iv = sigf(acc3[q][r]);
                const float fv = sigf(acc3[4 + q][r]);
                const float gv = tanh_(acc3[8 + q][r]);
                const float ov = sigf(acc3[12 + q][r]);
                c3[q][r] = fv * c3[q][r] + iv * gv;
                const float h = ov * tanh_(c3[q][r]);
                writeA(h1hi, h1lo, (kt * 64 + m + lup) * 8 + j, h);
            }
        }
        WB();
        // ---- dec2: gates4 = b4 + Whh4*h4[t-1] (VALU) + Wih4*h3[t] (2-term) ----
        a3h0 = *reinterpret_cast<const bf16x8*>(h1hi + lane * 8);
        a3h1 = *reinterpret_cast<const bf16x8*>(h1hi + (64 + lane) * 8);
        a3l0 = *reinterpret_cast<const bf16x8*>(h1lo + lane * 8);
        a3l1 = *reinterpret_cast<const bf16x8*>(h1lo + (64 + lane) * 8);
        f32x4 acc4 = splat4(bias4r);
        {
            const float4 w4 = *reinterpret_cast<const float4*>(W4hhF + col * 4);
#pragma unroll
            for (int r = 0; r < 4; ++r) {
                const float4 hv = *reinterpret_cast<const float4*>(bufH4 + (quad * 4 + r) * 4);
                float s = acc4[r];
                s = fmaf(w4.x, hv.x, s);
                s = fmaf(w4.y, hv.y, s);
                s = fmaf(w4.z, hv.z, s);
                s = fmaf(w4.w, hv.w, s);
                acc4[r] = s;
            }
        }
        {
            const bf16x8 bh0 = *reinterpret_cast<const bf16x8*>(Wih4hi + (0 * 64 + lane) * 8);
            const bf16x8 bh1 = *reinterpret_cast<const bf16x8*>(Wih4hi + (1 * 64 + lane) * 8);
            acc4 = MFMA(a3h0, bh0, acc4);
            acc4 = MFMA(a3l0, bh0, acc4);
            acc4 = MFMA(a3h1, bh1, acc4);
            acc4 = MFMA(a3l1, bh1, acc4);
        }
        WB();
#pragma unroll
        for (int r = 0; r < 4; ++r) gbuf[(quad * 4 + r) * 16 + col] = acc4[r];
        WB();
        // epilogue: lane = (batch mb, unit u4); no divergence
        {
            const float iv = sigf(gbuf[mb * 16 + u4]);
            const float fv = sigf(gbuf[mb * 16 + 4 + u4]);
            const float gv = tanh_(gbuf[mb * 16 + 8 + u4]);
            const float ov = sigf(gbuf[mb * 16 + 12 + u4]);
            c4 = fv * c4 + iv * gv;
            const float h = ov * tanh_(c4);
            out[((size_t)(b0w + mb) * TT + t) * IN + u4] = h;
            bufH4[mb * 4 + u4] = h;
        }
        WB();
    }
}

extern "C" void kernel_launch(void* const* d_in, const int* in_sizes, int n_in,
                              void* d_out, int out_size, void* d_ws, size_t ws_size,
                              hipStream_t stream) {
    (void)in_sizes; (void)n_in; (void)d_ws; (void)ws_size; (void)out_size;
    hipFuncSetAttribute(reinterpret_cast<const void*>(lstm_ae),
                        hipFuncAttributeMaxDynamicSharedMemorySize, SMEM_BYTES);
    const float* xi = (const float*)d_in[0];
    const float* w1ih = (const float*)d_in[1];
    const float* w1hh = (const float*)d_in[2];
    const float* b1i = (const float*)d_in[3];
    const float* b1h = (const float*)d_in[4];
    const float* w2ih = (const float*)d_in[5];
    const float* w2hh = (const float*)d_in[6];
    const float* b2i = (const float*)d_in[7];
    const float* b2h = (const float*)d_in[8];
    const float* w3ih = (const float*)d_in[9];
    const float* w3hh = (const float*)d_in[10];
    const float* b3i = (const float*)d_in[11];
    const float* b3h = (const float*)d_in[12];
    const float* w4ih = (const float*)d_in[13];
    const float* w4hh = (const float*)d_in[14];
    const float* b4i = (const float*)d_in[15];
    const float* b4h = (const float*)d_in[16];
    float* out = (float*)d_out;

    lstm_ae<<<dim3(BATCH / BPB), dim3(BLOCKT), SMEM_BYTES, stream>>>(
        xi, w1ih, w1hh, b1i, b1h, w2ih, w2hh, b2i, b2h,
        w3ih, w3hh, b3i, b3h, w4ih, w4hh, b4i, b4h, out);
}

// Round 9
// 388.351 us; speedup vs baseline: 4.7493x; 1.1487x over previous
//
#include <hip/hip_runtime.h>
#include <stdint.h>

// LSTM autoencoder B=32768 T=30 I=4 H=64 L=32, fp32 in/out.
// v9 = v8 (446us) issue-pressure cuts:
//  - 2-term MFMA everywhere (w bf16-hi only x (h_hi + h_lo)); v6==v8 absmax
//    bit-identity showed w_lo terms are below the noise floor.
//  - enc1's Wih1*x + bias1 folded into one extra MFMA k-tile (kt=2):
//    k0-3 xhi*whi | k4-7 xlo*whi | k8-11 xhi*wlo | k12,13 1.0*bias_hi/lo.
//    Replaces 256 VALU FMAs + 64 movs + 16 bias reads per enc-t.
//  - dec1 first MFMA consumes preactL as C (no 64-mov copy); enc1 acc
//    chains from a hoisted zero vector.
// Structure: 8 waves/block (512 thr), BPB=128, grid=256, 2 waves/SIMD.
// Layouts (HW-verified): C/D col=lane&15,row=(lane>>4)*4+reg [m89];
// A m=lane&15,k=(lane>>4)*8+j [m120]; B n=lane&15,k=(lane>>4)*8+j.

typedef unsigned short u16;
typedef unsigned int u32;
typedef __attribute__((ext_vector_type(8))) short bf16x8;
typedef __attribute__((ext_vector_type(4))) short s16x4;
typedef __attribute__((ext_vector_type(4))) float f32x4;

#define BATCH 32768
#define TT 30
#define IN 4
#define WAVES 8
#define BLOCKT (WAVES * 64)   // 512
#define MB 16
#define BPB (WAVES * MB)      // 128 batches/block -> grid 256, 1 round

// ---- LDS word (u32/float) offsets ----
#define WREG 18432
// enc phase
#define O_WHH1HI 0       // 8192 words (32 frags)
#define O_W1FOLD 8192    // 4096 words (16 frags: x+bias fold tile)
#define O_WIH2HI 12288   // 4096
#define O_WHH2HI 16384   // 2048 -> 18432
// dec phase (same region)
#define O_WHH3HI 0       // 8192
#define O_WIH3HI 8192    // 4096
#define O_WIH4HI 12288   // 512
#define O_W4HHF  12800   // 64 fp32 -> 12864

#define NBIAS 400   // b2[128] @0 | b3[256] @128 | b4[16] @384
// per-wave floats: h1hi 512 | h1lo 512 | xfold 256 | h2hi 256 | h2lo 256 | gbuf 256 | h4 64
#define BUFW 2112
#define SMEM_WORDS (WREG + NBIAS + WAVES * BUFW)   // 35728
#define SMEM_BYTES (SMEM_WORDS * 4)                // 142912 <= 163840

#define WB() __builtin_amdgcn_wave_barrier()
#define MFMA(a, b, c) __builtin_amdgcn_mfma_f32_16x16x32_bf16((a), (b), (c), 0, 0, 0)

__device__ __forceinline__ u16 f2bf(float f) {   // RNE fp32->bf16
    u32 u = __float_as_uint(f);
    u += 0x7fffu + ((u >> 16) & 1u);
    return (u16)(u >> 16);
}
__device__ __forceinline__ float bf2f(u16 v) { return __uint_as_float(((u32)v) << 16); }
__device__ __forceinline__ float sigf(float x) {
    return __builtin_amdgcn_rcpf(1.f + __expf(-x));
}
__device__ __forceinline__ float tanh_(float x) {
    const float t = __expf(2.f * x);
    return fmaf(-2.f, __builtin_amdgcn_rcpf(t + 1.f), 1.f);
}

// Stage fp32 W[N][K] -> bf16 hi, B-fragment order:
// u16 idx = ((nt*KT + kt)*64 + l)*8 + j, n = nt*16+(l&15), k = kt*32+((l>>4)<<3)+j
template <int KT>
__device__ __forceinline__ void stageBh(u16* hi, const float* src, int N, int tid) {
    const int K = KT * 32;
    const int total = N * K;
    for (int idx = tid; idx < total; idx += BLOCKT) {
        const int j = idx & 7;
        const int l = (idx >> 3) & 63;
        const int pair = idx >> 9;
        const int kt = pair & (KT - 1);
        const int nt = pair / KT;
        const int n = (nt << 4) | (l & 15);
        const int k = (kt << 5) + ((l >> 4) << 3) + j;
        hi[idx] = f2bf(src[n * K + k]);
    }
}

// write h into A-fragment layout: element (m,u): kt=u>>5, lup=16*((u>>3)&3), j=u&7
__device__ __forceinline__ void writeA(u16* Ahi, u16* Alo, int idx, float h) {
    const u16 hb = f2bf(h);
    Ahi[idx] = hb;
    Alo[idx] = f2bf(h - bf2f(hb));
}

__device__ __forceinline__ f32x4 splat4(float b) {
    f32x4 v = {b, b, b, b};
    return v;
}

__global__ __launch_bounds__(BLOCKT, 2) void lstm_ae(
    const float* __restrict__ x,
    const float* __restrict__ w1ih, const float* __restrict__ w1hh,
    const float* __restrict__ b1i, const float* __restrict__ b1h,
    const float* __restrict__ w2ih, const float* __restrict__ w2hh,
    const float* __restrict__ b2i, const float* __restrict__ b2h,
    const float* __restrict__ w3ih, const float* __restrict__ w3hh,
    const float* __restrict__ b3i, const float* __restrict__ b3h,
    const float* __restrict__ w4ih, const float* __restrict__ w4hh,
    const float* __restrict__ b4i, const float* __restrict__ b4h,
    float* __restrict__ out) {
    extern __shared__ float smem[];
    float* W = smem;
    float* biasF = smem + WREG;        // b2[128] b3[256] b4[16]
    float* bufs = biasF + NBIAS;

    const int tid = threadIdx.x;
    const int wave = tid >> 6, lane = tid & 63;
    const int col = lane & 15, quad = lane >> 4;

    float* wbuf = bufs + wave * BUFW;
    u16* h1hi = (u16*)(wbuf);          // 1024 u16 (h1/h3, A-layout, kt0..1)
    u16* h1lo = (u16*)(wbuf + 512);
    u16* xfold = (u16*)(wbuf + 1024);  // 512 u16 (enc1 kt=2 fold tile)
    u16* h2hi = (u16*)(wbuf + 1280);   // 512 u16 (h2/latent, kt0)
    u16* h2lo = (u16*)(wbuf + 1536);
    float* gbuf = wbuf + 1792;         // [16 batch][16 gate] fp32 (dec only)
    float* bufH4 = wbuf + 2048;        // [16 batch][4] fp32 (dec only)

    const int b0w = blockIdx.x * BPB + wave * MB;

    // ---------------- stage ENCODER weights + biases ----------------
    stageBh<2>((u16*)(W + O_WHH1HI), w1hh, 256, tid);
    stageBh<2>((u16*)(W + O_WIH2HI), w2ih, 128, tid);
    stageBh<1>((u16*)(W + O_WHH2HI), w2hh, 128, tid);
    // fold tile: B kt=2 per nt: k0-3 whi | k4-7 whi | k8-11 wlo | k12 bias_hi | k13 bias_lo
    {
        u16* F = (u16*)(W + O_W1FOLD);
        for (int idx = tid; idx < 16 * 512; idx += BLOCKT) {
            const int nt = idx >> 9;
            const int rem = idx & 511;
            const int l = rem >> 3;
            const int j = rem & 7;
            const int q = l >> 4;
            const int n = (nt << 4) | (l & 15);
            u16 v = 0;
            if (q == 0) {
                v = f2bf(w1ih[n * 4 + (j & 3)]);
            } else if (q == 1) {
                if (j < 4) {
                    const float w = w1ih[n * 4 + j];
                    v = f2bf(w - bf2f(f2bf(w)));
                } else if (j == 4) {
                    v = f2bf(b1i[n] + b1h[n]);
                } else if (j == 5) {
                    const float b = b1i[n] + b1h[n];
                    v = f2bf(b - bf2f(f2bf(b)));
                }
            }
            F[idx] = v;
        }
    }
    for (int i = tid; i < 128; i += BLOCKT) biasF[i] = b2i[i] + b2h[i];
    for (int i = tid; i < 256; i += BLOCKT) biasF[128 + i] = b3i[i] + b3h[i];
    for (int i = tid; i < 16; i += BLOCKT) biasF[384 + i] = b4i[i] + b4h[i];
    // zero wave buffers, then set the A kt=2 constant slots (1.0 at k12,k13)
    {
        u32* z = (u32*)wbuf;
        for (int i = lane; i < BUFW; i += 64) z[i] = 0u;
    }
    WB();
    if (quad == 1) {
        xfold[lane * 8 + 4] = (u16)0x3F80;   // bf16(1.0)
        xfold[lane * 8 + 5] = (u16)0x3F80;
    }
    __syncthreads();

    float bias2r[8];
#pragma unroll
    for (int nt = 0; nt < 8; ++nt) bias2r[nt] = biasF[nt * 16 + col];
    const float bias4r = biasF[384 + col];

    const u16* Whh1hi = (const u16*)(W + O_WHH1HI);
    const u16* W1fold = (const u16*)(W + O_W1FOLD);
    const u16* Wih2hi = (const u16*)(W + O_WIH2HI);
    const u16* Whh2hi = (const u16*)(W + O_WHH2HI);

    // ================= encoder =================
    float c1[4][4], c2[2][4];
#pragma unroll
    for (int q = 0; q < 4; ++q)
#pragma unroll
        for (int r = 0; r < 4; ++r) c1[q][r] = 0.f;
#pragma unroll
    for (int q = 0; q < 2; ++q)
#pragma unroll
        for (int r = 0; r < 4; ++r) c2[q][r] = 0.f;

    const f32x4 zf = {0.f, 0.f, 0.f, 0.f};
    // x for batch (lane&15); lanes>=32 load too (harmless, coalesced/L1)
    float4 xcur = *reinterpret_cast<const float4*>(
        x + ((size_t)(b0w + col) * TT + 0) * IN);

    for (int t = 0; t < TT; ++t) {
        // ---- write x (+const bias slots) into the kt=2 A tile ----
        {
            const u16 xh0 = f2bf(xcur.x), xh1 = f2bf(xcur.y);
            const u16 xh2 = f2bf(xcur.z), xh3 = f2bf(xcur.w);
            if (quad == 0) {
                bf16x8 v;
                v[0] = (short)xh0; v[1] = (short)xh1; v[2] = (short)xh2; v[3] = (short)xh3;
                v[4] = (short)f2bf(xcur.x - bf2f(xh0));
                v[5] = (short)f2bf(xcur.y - bf2f(xh1));
                v[6] = (short)f2bf(xcur.z - bf2f(xh2));
                v[7] = (short)f2bf(xcur.w - bf2f(xh3));
                *reinterpret_cast<bf16x8*>(xfold + lane * 8) = v;
            } else if (quad == 1) {
                s16x4 v;
                v[0] = (short)xh0; v[1] = (short)xh1; v[2] = (short)xh2; v[3] = (short)xh3;
                *reinterpret_cast<s16x4*>(xfold + lane * 8) = v;
            }
        }
        WB();
        // prefetch next x
        {
            const int tn = (t + 1 < TT) ? t + 1 : t;
            xcur = *reinterpret_cast<const float4*>(
                x + ((size_t)(b0w + col) * TT + tn) * IN);
        }
        // ---- enc1: gates1 = fold(x,bias) + Whh1*h1[t-1], 5 MFMA/nt ----
        bf16x8 a1h0 = *reinterpret_cast<const bf16x8*>(h1hi + lane * 8);
        bf16x8 a1h1 = *reinterpret_cast<const bf16x8*>(h1hi + (64 + lane) * 8);
        bf16x8 a1l0 = *reinterpret_cast<const bf16x8*>(h1lo + lane * 8);
        bf16x8 a1l1 = *reinterpret_cast<const bf16x8*>(h1lo + (64 + lane) * 8);
        const bf16x8 a1x = *reinterpret_cast<const bf16x8*>(xfold + lane * 8);
        f32x4 acc1[16];
#pragma unroll
        for (int nt = 0; nt < 16; ++nt) {
            const bf16x8 bx = *reinterpret_cast<const bf16x8*>(W1fold + (nt * 64 + lane) * 8);
            const bf16x8 bh0 = *reinterpret_cast<const bf16x8*>(Whh1hi + ((nt * 2 + 0) * 64 + lane) * 8);
            const bf16x8 bh1 = *reinterpret_cast<const bf16x8*>(Whh1hi + ((nt * 2 + 1) * 64 + lane) * 8);
            f32x4 a = MFMA(a1x, bx, zf);
            a = MFMA(a1h0, bh0, a);
            a = MFMA(a1l0, bh0, a);
            a = MFMA(a1h1, bh1, a);
            a = MFMA(a1l1, bh1, a);
            acc1[nt] = a;
        }
        WB();
#pragma unroll
        for (int q = 0; q < 4; ++q) {   // h1[t] -> A-layout
            const int kt = q >> 1;
            const int lup = ((((q & 1) << 1) + (col >> 3)) << 4);
            const int j = col & 7;
#pragma unroll
            for (int r = 0; r < 4; ++r) {
                const int m = quad * 4 + r;
                const float iv = sigf(acc1[q][r]);
                const float fv = sigf(acc1[4 + q][r]);
                const float gv = tanh_(acc1[8 + q][r]);
                const float ov = sigf(acc1[12 + q][r]);
                c1[q][r] = fv * c1[q][r] + iv * gv;
                const float h = ov * tanh_(c1[q][r]);
                writeA(h1hi, h1lo, (kt * 64 + m + lup) * 8 + j, h);
            }
        }
        WB();
        // ---- enc2: gates2 = b2 + Wih2*h1[t] + Whh2*h2[t-1] (2-term) ----
        a1h0 = *reinterpret_cast<const bf16x8*>(h1hi + lane * 8);
        a1h1 = *reinterpret_cast<const bf16x8*>(h1hi + (64 + lane) * 8);
        a1l0 = *reinterpret_cast<const bf16x8*>(h1lo + lane * 8);
        a1l1 = *reinterpret_cast<const bf16x8*>(h1lo + (64 + lane) * 8);
        const bf16x8 a2h = *reinterpret_cast<const bf16x8*>(h2hi + lane * 8);
        const bf16x8 a2l = *reinterpret_cast<const bf16x8*>(h2lo + lane * 8);
        f32x4 acc2[8];
#pragma unroll
        for (int nt = 0; nt < 8; ++nt) {
            const bf16x8 bh0 = *reinterpret_cast<const bf16x8*>(Wih2hi + ((nt * 2 + 0) * 64 + lane) * 8);
            const bf16x8 bh1 = *reinterpret_cast<const bf16x8*>(Wih2hi + ((nt * 2 + 1) * 64 + lane) * 8);
            const bf16x8 ch = *reinterpret_cast<const bf16x8*>(Whh2hi + (nt * 64 + lane) * 8);
            f32x4 a = splat4(bias2r[nt]);
            a = MFMA(a1h0, bh0, a);
            a = MFMA(a1l0, bh0, a);
            a = MFMA(a1h1, bh1, a);
            a = MFMA(a1l1, bh1, a);
            a = MFMA(a2h, ch, a);
            a = MFMA(a2l, ch, a);
            acc2[nt] = a;
        }
        WB();
#pragma unroll
        for (int q = 0; q < 2; ++q) {   // h2[t] -> A-layout (kt=0)
            const int lup = (((q << 1) + (col >> 3)) << 4);
            const int j = col & 7;
#pragma unroll
            for (int r = 0; r < 4; ++r) {
                const int m = quad * 4 + r;
                const float iv = sigf(acc2[q][r]);
                const float fv = sigf(acc2[2 + q][r]);
                const float gv = tanh_(acc2[4 + q][r]);
                const float ov = sigf(acc2[6 + q][r]);
                c2[q][r] = fv * c2[q][r] + iv * gv;
                const float h = ov * tanh_(c2[q][r]);
                writeA(h2hi, h2lo, (m + lup) * 8 + j, h);
            }
        }
        WB();
    }
    // h2 buffers now hold the latent (read-only below).

    __syncthreads();   // all waves done with encoder weights

    // ---------------- re-stage DECODER weights ----------------
    stageBh<2>((u16*)(W + O_WHH3HI), w3hh, 256, tid);
    stageBh<1>((u16*)(W + O_WIH3HI), w3ih, 256, tid);
    stageBh<2>((u16*)(W + O_WIH4HI), w4ih, 16, tid);
    for (int i = tid; i < 64; i += BLOCKT) W[O_W4HHF + i] = w4hh[i];
    // zero h3 (h1 slot) + h4 state
    {
        u32* z = (u32*)wbuf;
        for (int i = lane; i < 1024; i += 64) z[i] = 0u;
        if (lane < 64) bufH4[lane] = 0.f;
    }
    __syncthreads();

    const u16* Whh3hi = (const u16*)(W + O_WHH3HI);
    const u16* Wih3hi = (const u16*)(W + O_WIH3HI);
    const u16* Wih4hi = (const u16*)(W + O_WIH4HI);
    const float* W4hhF = W + O_W4HHF;

    // preactL = b3 + Wih3 * latent (constant over t, 2-term)
    f32x4 preactL[16];
    {
        const bf16x8 aLh = *reinterpret_cast<const bf16x8*>(h2hi + lane * 8);
        const bf16x8 aLl = *reinterpret_cast<const bf16x8*>(h2lo + lane * 8);
#pragma unroll
        for (int nt = 0; nt < 16; ++nt) {
            const bf16x8 bh = *reinterpret_cast<const bf16x8*>(Wih3hi + (nt * 64 + lane) * 8);
            f32x4 a = splat4(biasF[128 + nt * 16 + col]);
            a = MFMA(aLh, bh, a);
            a = MFMA(aLl, bh, a);
            preactL[nt] = a;
        }
    }

    float c3[4][4], c4 = 0.f;
#pragma unroll
    for (int q = 0; q < 4; ++q)
#pragma unroll
        for (int r = 0; r < 4; ++r) c3[q][r] = 0.f;
    const int u4 = lane & 3, mb = lane >> 2;   // dec2 epilogue task

    for (int t = 0; t < TT; ++t) {
        // ---- dec1: gates3 = preactL + Whh3*h3[t-1] (2-term) ----
        bf16x8 a3h0 = *reinterpret_cast<const bf16x8*>(h1hi + lane * 8);
        bf16x8 a3h1 = *reinterpret_cast<const bf16x8*>(h1hi + (64 + lane) * 8);
        bf16x8 a3l0 = *reinterpret_cast<const bf16x8*>(h1lo + lane * 8);
        bf16x8 a3l1 = *reinterpret_cast<const bf16x8*>(h1lo + (64 + lane) * 8);
        f32x4 acc3[16];
#pragma unroll
        for (int nt = 0; nt < 16; ++nt) {
            const bf16x8 bh0 = *reinterpret_cast<const bf16x8*>(Whh3hi + ((nt * 2 + 0) * 64 + lane) * 8);
            const bf16x8 bh1 = *reinterpret_cast<const bf16x8*>(Whh3hi + ((nt * 2 + 1) * 64 + lane) * 8);
            f32x4 a = MFMA(a3h0, bh0, preactL[nt]);
            a = MFMA(a3l0, bh0, a);
            a = MFMA(a3h1, bh1, a);
            a = MFMA(a3l1, bh1, a);
            acc3[nt] = a;
        }
        WB();
#pragma unroll
        for (int q = 0; q < 4; ++q) {   // h3[t] -> A-layout
            const int kt = q >> 1;
            const int lup = ((((q & 1) << 1) + (col >> 3)) << 4);
            const int j = col & 7;
#pragma unroll
            for (int r = 0; r < 4; ++r) {
                const int m = quad * 4 + r;
                const float iv = sigf(acc3[q][r]);
                const float fv = sigf(acc3[4 + q][r]);
                const float gv = tanh_(acc3[8 + q][r]);
                const float ov = sigf(acc3[12 + q][r]);
                c3[q][r] = fv * c3[q][r] + iv * gv;
                const float h = ov * tanh_(c3[q][r]);
                writeA(h1hi, h1lo, (kt * 64 + m + lup) * 8 + j, h);
            }
        }
        WB();
        // ---- dec2: gates4 = b4 + Whh4*h4[t-1] (VALU) + Wih4*h3[t] (2-term) ----
        a3h0 = *reinterpret_cast<const bf16x8*>(h1hi + lane * 8);
        a3h1 = *reinterpret_cast<const bf16x8*>(h1hi + (64 + lane) * 8);
        a3l0 = *reinterpret_cast<const bf16x8*>(h1lo + lane * 8);
        a3l1 = *reinterpret_cast<const bf16x8*>(h1lo + (64 + lane) * 8);
        f32x4 acc4 = splat4(bias4r);
        {
            const float4 w4 = *reinterpret_cast<const float4*>(W4hhF + col * 4);
#pragma unroll
            for (int r = 0; r < 4; ++r) {
                const float4 hv = *reinterpret_cast<const float4*>(bufH4 + (quad * 4 + r) * 4);
                float s = acc4[r];
                s = fmaf(w4.x, hv.x, s);
                s = fmaf(w4.y, hv.y, s);
                s = fmaf(w4.z, hv.z, s);
                s = fmaf(w4.w, hv.w, s);
                acc4[r] = s;
            }
        }
        {
            const bf16x8 bh0 = *reinterpret_cast<const bf16x8*>(Wih4hi + (0 * 64 + lane) * 8);
            const bf16x8 bh1 = *reinterpret_cast<const bf16x8*>(Wih4hi + (1 * 64 + lane) * 8);
            acc4 = MFMA(a3h0, bh0, acc4);
            acc4 = MFMA(a3l0, bh0, acc4);
            acc4 = MFMA(a3h1, bh1, acc4);
            acc4 = MFMA(a3l1, bh1, acc4);
        }
        WB();
#pragma unroll
        for (int r = 0; r < 4; ++r) gbuf[(quad * 4 + r) * 16 + col] = acc4[r];
        WB();
        // epilogue: lane = (batch mb, unit u4); no divergence
        {
            const float iv = sigf(gbuf[mb * 16 + u4]);
            const float fv = sigf(gbuf[mb * 16 + 4 + u4]);
            const float gv = tanh_(gbuf[mb * 16 + 8 + u4]);
            const float ov = sigf(gbuf[mb * 16 + 12 + u4]);
            c4 = fv * c4 + iv * gv;
            const float h = ov * tanh_(c4);
            out[((size_t)(b0w + mb) * TT + t) * IN + u4] = h;
            bufH4[mb * 4 + u4] = h;
        }
        WB();
    }
}

extern "C" void kernel_launch(void* const* d_in, const int* in_sizes, int n_in,
                              void* d_out, int out_size, void* d_ws, size_t ws_size,
                              hipStream_t stream) {
    (void)in_sizes; (void)n_in; (void)d_ws; (void)ws_size; (void)out_size;
    hipFuncSetAttribute(reinterpret_cast<const void*>(lstm_ae),
                        hipFuncAttributeMaxDynamicSharedMemorySize, SMEM_BYTES);
    const float* xi = (const float*)d_in[0];
    const float* w1ih = (const float*)d_in[1];
    const float* w1hh = (const float*)d_in[2];
    const float* b1i = (const float*)d_in[3];
    const float* b1h = (const float*)d_in[4];
    const float* w2ih = (const float*)d_in[5];
    const float* w2hh = (const float*)d_in[6];
    const float* b2i = (const float*)d_in[7];
    const float* b2h = (const float*)d_in[8];
    const float* w3ih = (const float*)d_in[9];
    const float* w3hh = (const float*)d_in[10];
    const float* b3i = (const float*)d_in[11];
    const float* b3h = (const float*)d_in[12];
    const float* w4ih = (const float*)d_in[13];
    const float* w4hh = (const float*)d_in[14];
    const float* b4i = (const float*)d_in[15];
    const float* b4h = (const float*)d_in[16];
    float* out = (float*)d_out;

    lstm_ae<<<dim3(BATCH / BPB), dim3(BLOCKT), SMEM_BYTES, stream>>>(
        xi, w1ih, w1hh, b1i, b1h, w2ih, w2hh, b2i, b2h,
        w3ih, w3hh, b3i, b3h, w4ih, w4hh, b4i, b4h, out);
}

// Round 10
// 340.913 us; speedup vs baseline: 5.4102x; 1.1392x over previous
//
#include <hip/hip_runtime.h>
#include <stdint.h>

// LSTM autoencoder B=32768 T=30 I=4 H=64 L=32, fp32 in/out.
// v10 = v9 (388us) with h_lo dropped everywhere (1-term: bf16 h x bf16 w_hi).
// Rationale: absmax has been bit-identical to pure-fp32 (2^-10, the __expf
// floor) through 3-term and 2-term variants -> lo terms are below the noise.
// Cuts ~40% of MFMAs, ~45% of fragment ds_reads, and one convert+ds_write
// per h-store. LDS 142.9 -> 118.3 KB. Structure unchanged: 8 waves/block,
// BPB=128, grid=256, 2 waves/SIMD, enc1 x+bias folded as MFMA k-tile.
// Layouts (HW-verified): C/D col=lane&15,row=(lane>>4)*4+reg [m89];
// A m=lane&15,k=(lane>>4)*8+j [m120]; B n=lane&15,k=(lane>>4)*8+j.

typedef unsigned short u16;
typedef unsigned int u32;
typedef __attribute__((ext_vector_type(8))) short bf16x8;
typedef __attribute__((ext_vector_type(4))) short s16x4;
typedef __attribute__((ext_vector_type(4))) float f32x4;

#define BATCH 32768
#define TT 30
#define IN 4
#define WAVES 8
#define BLOCKT (WAVES * 64)   // 512
#define MB 16
#define BPB (WAVES * MB)      // 128 batches/block -> grid 256, 1 round

// ---- LDS word (u32/float) offsets ----
#define WREG 18432
// enc phase
#define O_WHH1HI 0       // 8192 words (32 frags)
#define O_W1FOLD 8192    // 4096 words (16 frags: x+bias fold tile)
#define O_WIH2HI 12288   // 4096
#define O_WHH2HI 16384   // 2048 -> 18432
// dec phase (same region)
#define O_WHH3HI 0       // 8192
#define O_WIH3HI 8192    // 4096
#define O_WIH4HI 12288   // 512
#define O_W4HHF  12800   // 64 fp32 -> 12864

#define NBIAS 400   // b2[128] @0 | b3[256] @128 | b4[16] @384
// per-wave floats: h1hi 512 | xfold 256 | h2hi 256 | gbuf 256 | h4 64
#define BUFW 1344
#define SMEM_WORDS (WREG + NBIAS + WAVES * BUFW)   // 29584
#define SMEM_BYTES (SMEM_WORDS * 4)                // 118336 <= 163840

#define WB() __builtin_amdgcn_wave_barrier()
#define MFMA(a, b, c) __builtin_amdgcn_mfma_f32_16x16x32_bf16((a), (b), (c), 0, 0, 0)

__device__ __forceinline__ u16 f2bf(float f) {   // RNE fp32->bf16
    u32 u = __float_as_uint(f);
    u += 0x7fffu + ((u >> 16) & 1u);
    return (u16)(u >> 16);
}
__device__ __forceinline__ float bf2f(u16 v) { return __uint_as_float(((u32)v) << 16); }
__device__ __forceinline__ float sigf(float x) {
    return __builtin_amdgcn_rcpf(1.f + __expf(-x));
}
__device__ __forceinline__ float tanh_(float x) {
    const float t = __expf(2.f * x);
    return fmaf(-2.f, __builtin_amdgcn_rcpf(t + 1.f), 1.f);
}

// Stage fp32 W[N][K] -> bf16 hi, B-fragment order:
// u16 idx = ((nt*KT + kt)*64 + l)*8 + j, n = nt*16+(l&15), k = kt*32+((l>>4)<<3)+j
template <int KT>
__device__ __forceinline__ void stageBh(u16* hi, const float* src, int N, int tid) {
    const int K = KT * 32;
    const int total = N * K;
    for (int idx = tid; idx < total; idx += BLOCKT) {
        const int j = idx & 7;
        const int l = (idx >> 3) & 63;
        const int pair = idx >> 9;
        const int kt = pair & (KT - 1);
        const int nt = pair / KT;
        const int n = (nt << 4) | (l & 15);
        const int k = (kt << 5) + ((l >> 4) << 3) + j;
        hi[idx] = f2bf(src[n * K + k]);
    }
}

__device__ __forceinline__ f32x4 splat4(float b) {
    f32x4 v = {b, b, b, b};
    return v;
}

__global__ __launch_bounds__(BLOCKT, 2) void lstm_ae(
    const float* __restrict__ x,
    const float* __restrict__ w1ih, const float* __restrict__ w1hh,
    const float* __restrict__ b1i, const float* __restrict__ b1h,
    const float* __restrict__ w2ih, const float* __restrict__ w2hh,
    const float* __restrict__ b2i, const float* __restrict__ b2h,
    const float* __restrict__ w3ih, const float* __restrict__ w3hh,
    const float* __restrict__ b3i, const float* __restrict__ b3h,
    const float* __restrict__ w4ih, const float* __restrict__ w4hh,
    const float* __restrict__ b4i, const float* __restrict__ b4h,
    float* __restrict__ out) {
    extern __shared__ float smem[];
    float* W = smem;
    float* biasF = smem + WREG;        // b2[128] b3[256] b4[16]
    float* bufs = biasF + NBIAS;

    const int tid = threadIdx.x;
    const int wave = tid >> 6, lane = tid & 63;
    const int col = lane & 15, quad = lane >> 4;

    float* wbuf = bufs + wave * BUFW;
    u16* h1hi = (u16*)(wbuf);          // 1024 u16 (h1/h3, A-layout, kt0..1)
    u16* xfold = (u16*)(wbuf + 512);   // 512 u16 (enc1 kt=2 fold tile)
    u16* h2hi = (u16*)(wbuf + 768);    // 512 u16 (h2/latent, kt0)
    float* gbuf = wbuf + 1024;         // [16 batch][16 gate] fp32 (dec only)
    float* bufH4 = wbuf + 1280;        // [16 batch][4] fp32 (dec only)

    const int b0w = blockIdx.x * BPB + wave * MB;

    // ---------------- stage ENCODER weights + biases ----------------
    stageBh<2>((u16*)(W + O_WHH1HI), w1hh, 256, tid);
    stageBh<2>((u16*)(W + O_WIH2HI), w2ih, 128, tid);
    stageBh<1>((u16*)(W + O_WHH2HI), w2hh, 128, tid);
    // fold tile: B kt=2 per nt: k0-3 whi | k4-7 whi | k8-11 wlo | k12 bias_hi | k13 bias_lo
    {
        u16* F = (u16*)(W + O_W1FOLD);
        for (int idx = tid; idx < 16 * 512; idx += BLOCKT) {
            const int nt = idx >> 9;
            const int rem = idx & 511;
            const int l = rem >> 3;
            const int j = rem & 7;
            const int q = l >> 4;
            const int n = (nt << 4) | (l & 15);
            u16 v = 0;
            if (q == 0) {
                v = f2bf(w1ih[n * 4 + (j & 3)]);
            } else if (q == 1) {
                if (j < 4) {
                    const float w = w1ih[n * 4 + j];
                    v = f2bf(w - bf2f(f2bf(w)));
                } else if (j == 4) {
                    v = f2bf(b1i[n] + b1h[n]);
                } else if (j == 5) {
                    const float b = b1i[n] + b1h[n];
                    v = f2bf(b - bf2f(f2bf(b)));
                }
            }
            F[idx] = v;
        }
    }
    for (int i = tid; i < 128; i += BLOCKT) biasF[i] = b2i[i] + b2h[i];
    for (int i = tid; i < 256; i += BLOCKT) biasF[128 + i] = b3i[i] + b3h[i];
    for (int i = tid; i < 16; i += BLOCKT) biasF[384 + i] = b4i[i] + b4h[i];
    // zero wave buffers, then set the A kt=2 constant slots (1.0 at k12,k13)
    {
        u32* z = (u32*)wbuf;
        for (int i = lane; i < BUFW; i += 64) z[i] = 0u;
    }
    WB();
    if (quad == 1) {
        xfold[lane * 8 + 4] = (u16)0x3F80;   // bf16(1.0)
        xfold[lane * 8 + 5] = (u16)0x3F80;
    }
    __syncthreads();

    float bias2r[8];
#pragma unroll
    for (int nt = 0; nt < 8; ++nt) bias2r[nt] = biasF[nt * 16 + col];
    const float bias4r = biasF[384 + col];

    const u16* Whh1hi = (const u16*)(W + O_WHH1HI);
    const u16* W1fold = (const u16*)(W + O_W1FOLD);
    const u16* Wih2hi = (const u16*)(W + O_WIH2HI);
    const u16* Whh2hi = (const u16*)(W + O_WHH2HI);

    // ================= encoder =================
    float c1[4][4], c2[2][4];
#pragma unroll
    for (int q = 0; q < 4; ++q)
#pragma unroll
        for (int r = 0; r < 4; ++r) c1[q][r] = 0.f;
#pragma unroll
    for (int q = 0; q < 2; ++q)
#pragma unroll
        for (int r = 0; r < 4; ++r) c2[q][r] = 0.f;

    const f32x4 zf = {0.f, 0.f, 0.f, 0.f};
    float4 xcur = *reinterpret_cast<const float4*>(
        x + ((size_t)(b0w + col) * TT + 0) * IN);

    for (int t = 0; t < TT; ++t) {
        // ---- write x (+const bias slots) into the kt=2 A tile ----
        {
            const u16 xh0 = f2bf(xcur.x), xh1 = f2bf(xcur.y);
            const u16 xh2 = f2bf(xcur.z), xh3 = f2bf(xcur.w);
            if (quad == 0) {
                bf16x8 v;
                v[0] = (short)xh0; v[1] = (short)xh1; v[2] = (short)xh2; v[3] = (short)xh3;
                v[4] = (short)f2bf(xcur.x - bf2f(xh0));
                v[5] = (short)f2bf(xcur.y - bf2f(xh1));
                v[6] = (short)f2bf(xcur.z - bf2f(xh2));
                v[7] = (short)f2bf(xcur.w - bf2f(xh3));
                *reinterpret_cast<bf16x8*>(xfold + lane * 8) = v;
            } else if (quad == 1) {
                s16x4 v;
                v[0] = (short)xh0; v[1] = (short)xh1; v[2] = (short)xh2; v[3] = (short)xh3;
                *reinterpret_cast<s16x4*>(xfold + lane * 8) = v;
            }
        }
        WB();
        // prefetch next x
        {
            const int tn = (t + 1 < TT) ? t + 1 : t;
            xcur = *reinterpret_cast<const float4*>(
                x + ((size_t)(b0w + col) * TT + tn) * IN);
        }
        // ---- enc1: gates1 = fold(x,bias) + Whh1*h1[t-1], 3 MFMA/nt ----
        bf16x8 a1h0 = *reinterpret_cast<const bf16x8*>(h1hi + lane * 8);
        bf16x8 a1h1 = *reinterpret_cast<const bf16x8*>(h1hi + (64 + lane) * 8);
        const bf16x8 a1x = *reinterpret_cast<const bf16x8*>(xfold + lane * 8);
        f32x4 acc1[16];
#pragma unroll
        for (int nt = 0; nt < 16; ++nt) {
            const bf16x8 bx = *reinterpret_cast<const bf16x8*>(W1fold + (nt * 64 + lane) * 8);
            const bf16x8 bh0 = *reinterpret_cast<const bf16x8*>(Whh1hi + ((nt * 2 + 0) * 64 + lane) * 8);
            const bf16x8 bh1 = *reinterpret_cast<const bf16x8*>(Whh1hi + ((nt * 2 + 1) * 64 + lane) * 8);
            f32x4 a = MFMA(a1x, bx, zf);
            a = MFMA(a1h0, bh0, a);
            a = MFMA(a1h1, bh1, a);
            acc1[nt] = a;
        }
        WB();
#pragma unroll
        for (int q = 0; q < 4; ++q) {   // h1[t] -> A-layout
            const int kt = q >> 1;
            const int lup = ((((q & 1) << 1) + (col >> 3)) << 4);
            const int j = col & 7;
#pragma unroll
            for (int r = 0; r < 4; ++r) {
                const int m = quad * 4 + r;
                const float iv = sigf(acc1[q][r]);
                const float fv = sigf(acc1[4 + q][r]);
                const float gv = tanh_(acc1[8 + q][r]);
                const float ov = sigf(acc1[12 + q][r]);
                c1[q][r] = fv * c1[q][r] + iv * gv;
                const float h = ov * tanh_(c1[q][r]);
                h1hi[(kt * 64 + m + lup) * 8 + j] = f2bf(h);
            }
        }
        WB();
        // ---- enc2: gates2 = b2 + Wih2*h1[t] + Whh2*h2[t-1] (1-term) ----
        a1h0 = *reinterpret_cast<const bf16x8*>(h1hi + lane * 8);
        a1h1 = *reinterpret_cast<const bf16x8*>(h1hi + (64 + lane) * 8);
        const bf16x8 a2h = *reinterpret_cast<const bf16x8*>(h2hi + lane * 8);
        f32x4 acc2[8];
#pragma unroll
        for (int nt = 0; nt < 8; ++nt) {
            const bf16x8 bh0 = *reinterpret_cast<const bf16x8*>(Wih2hi + ((nt * 2 + 0) * 64 + lane) * 8);
            const bf16x8 bh1 = *reinterpret_cast<const bf16x8*>(Wih2hi + ((nt * 2 + 1) * 64 + lane) * 8);
            const bf16x8 ch = *reinterpret_cast<const bf16x8*>(Whh2hi + (nt * 64 + lane) * 8);
            f32x4 a = splat4(bias2r[nt]);
            a = MFMA(a1h0, bh0, a);
            a = MFMA(a1h1, bh1, a);
            a = MFMA(a2h, ch, a);
            acc2[nt] = a;
        }
        WB();
#pragma unroll
        for (int q = 0; q < 2; ++q) {   // h2[t] -> A-layout (kt=0)
            const int lup = (((q << 1) + (col >> 3)) << 4);
            const int j = col & 7;
#pragma unroll
            for (int r = 0; r < 4; ++r) {
                const int m = quad * 4 + r;
                const float iv = sigf(acc2[q][r]);
                const float fv = sigf(acc2[2 + q][r]);
                const float gv = tanh_(acc2[4 + q][r]);
                const float ov = sigf(acc2[6 + q][r]);
                c2[q][r] = fv * c2[q][r] + iv * gv;
                const float h = ov * tanh_(c2[q][r]);
                h2hi[(m + lup) * 8 + j] = f2bf(h);
            }
        }
        WB();
    }
    // h2 buffer now holds the latent (read-only below).

    __syncthreads();   // all waves done with encoder weights

    // ---------------- re-stage DECODER weights ----------------
    stageBh<2>((u16*)(W + O_WHH3HI), w3hh, 256, tid);
    stageBh<1>((u16*)(W + O_WIH3HI), w3ih, 256, tid);
    stageBh<2>((u16*)(W + O_WIH4HI), w4ih, 16, tid);
    for (int i = tid; i < 64; i += BLOCKT) W[O_W4HHF + i] = w4hh[i];
    // zero h3 (h1 slot) + h4 state
    {
        u32* z = (u32*)wbuf;
        for (int i = lane; i < 512; i += 64) z[i] = 0u;
        if (lane < 64) bufH4[lane] = 0.f;
    }
    __syncthreads();

    const u16* Whh3hi = (const u16*)(W + O_WHH3HI);
    const u16* Wih3hi = (const u16*)(W + O_WIH3HI);
    const u16* Wih4hi = (const u16*)(W + O_WIH4HI);
    const float* W4hhF = W + O_W4HHF;

    // preactL = b3 + Wih3 * latent (constant over t, 1-term)
    f32x4 preactL[16];
    {
        const bf16x8 aLh = *reinterpret_cast<const bf16x8*>(h2hi + lane * 8);
#pragma unroll
        for (int nt = 0; nt < 16; ++nt) {
            const bf16x8 bh = *reinterpret_cast<const bf16x8*>(Wih3hi + (nt * 64 + lane) * 8);
            preactL[nt] = MFMA(aLh, bh, splat4(biasF[128 + nt * 16 + col]));
        }
    }

    float c3[4][4], c4 = 0.f;
#pragma unroll
    for (int q = 0; q < 4; ++q)
#pragma unroll
        for (int r = 0; r < 4; ++r) c3[q][r] = 0.f;
    const int u4 = lane & 3, mb = lane >> 2;   // dec2 epilogue task

    for (int t = 0; t < TT; ++t) {
        // ---- dec1: gates3 = preactL + Whh3*h3[t-1] (1-term) ----
        bf16x8 a3h0 = *reinterpret_cast<const bf16x8*>(h1hi + lane * 8);
        bf16x8 a3h1 = *reinterpret_cast<const bf16x8*>(h1hi + (64 + lane) * 8);
        f32x4 acc3[16];
#pragma unroll
        for (int nt = 0; nt < 16; ++nt) {
            const bf16x8 bh0 = *reinterpret_cast<const bf16x8*>(Whh3hi + ((nt * 2 + 0) * 64 + lane) * 8);
            const bf16x8 bh1 = *reinterpret_cast<const bf16x8*>(Whh3hi + ((nt * 2 + 1) * 64 + lane) * 8);
            f32x4 a = MFMA(a3h0, bh0, preactL[nt]);
            a = MFMA(a3h1, bh1, a);
            acc3[nt] = a;
        }
        WB();
#pragma unroll
        for (int q = 0; q < 4; ++q) {   // h3[t] -> A-layout
            const int kt = q >> 1;
            const int lup = ((((q & 1) << 1) + (col >> 3)) << 4);
            const int j = col & 7;
#pragma unroll
            for (int r = 0; r < 4; ++r) {
                const int m = quad * 4 + r;
                const float iv = sigf(acc3[q][r]);
                const float fv = sigf(acc3[4 + q][r]);
                const float gv = tanh_(acc3[8 + q][r]);
                const float ov = sigf(acc3[12 + q][r]);
                c3[q][r] = fv * c3[q][r] + iv * gv;
                const float h = ov * tanh_(c3[q][r]);
                h1hi[(kt * 64 + m + lup) * 8 + j] = f2bf(h);
            }
        }
        WB();
        // ---- dec2: gates4 = b4 + Whh4*h4[t-1] (VALU) + Wih4*h3[t] (1-term) ----
        a3h0 = *reinterpret_cast<const bf16x8*>(h1hi + lane * 8);
        a3h1 = *reinterpret_cast<const bf16x8*>(h1hi + (64 + lane) * 8);
        f32x4 acc4 = splat4(bias4r);
        {
            const float4 w4 = *reinterpret_cast<const float4*>(W4hhF + col * 4);
#pragma unroll
            for (int r = 0; r < 4; ++r) {
                const float4 hv = *reinterpret_cast<const float4*>(bufH4 + (quad * 4 + r) * 4);
                float s = acc4[r];
                s = fmaf(w4.x, hv.x, s);
                s = fmaf(w4.y, hv.y, s);
                s = fmaf(w4.z, hv.z, s);
                s = fmaf(w4.w, hv.w, s);
                acc4[r] = s;
            }
        }
        {
            const bf16x8 bh0 = *reinterpret_cast<const bf16x8*>(Wih4hi + (0 * 64 + lane) * 8);
            const bf16x8 bh1 = *reinterpret_cast<const bf16x8*>(Wih4hi + (1 * 64 + lane) * 8);
            acc4 = MFMA(a3h0, bh0, acc4);
            acc4 = MFMA(a3h1, bh1, acc4);
        }
        WB();
#pragma unroll
        for (int r = 0; r < 4; ++r) gbuf[(quad * 4 + r) * 16 + col] = acc4[r];
        WB();
        // epilogue: lane = (batch mb, unit u4); no divergence
        {
            const float iv = sigf(gbuf[mb * 16 + u4]);
            const float fv = sigf(gbuf[mb * 16 + 4 + u4]);
            const float gv = tanh_(gbuf[mb * 16 + 8 + u4]);
            const float ov = sigf(gbuf[mb * 16 + 12 + u4]);
            c4 = fv * c4 + iv * gv;
            const float h = ov * tanh_(c4);
            out[((size_t)(b0w + mb) * TT + t) * IN + u4] = h;
            bufH4[mb * 4 + u4] = h;
        }
        WB();
    }
}

extern "C" void kernel_launch(void* const* d_in, const int* in_sizes, int n_in,
                              void* d_out, int out_size, void* d_ws, size_t ws_size,
                              hipStream_t stream) {
    (void)in_sizes; (void)n_in; (void)d_ws; (void)ws_size; (void)out_size;
    hipFuncSetAttribute(reinterpret_cast<const void*>(lstm_ae),
                        hipFuncAttributeMaxDynamicSharedMemorySize, SMEM_BYTES);
    const float* xi = (const float*)d_in[0];
    const float* w1ih = (const float*)d_in[1];
    const float* w1hh = (const float*)d_in[2];
    const float* b1i = (const float*)d_in[3];
    const float* b1h = (const float*)d_in[4];
    const float* w2ih = (const float*)d_in[5];
    const float* w2hh = (const float*)d_in[6];
    const float* b2i = (const float*)d_in[7];
    const float* b2h = (const float*)d_in[8];
    const float* w3ih = (const float*)d_in[9];
    const float* w3hh = (const float*)d_in[10];
    const float* b3i = (const float*)d_in[11];
    const float* b3h = (const float*)d_in[12];
    const float* w4ih = (const float*)d_in[13];
    const float* w4hh = (const float*)d_in[14];
    const float* b4i = (const float*)d_in[15];
    const float* b4h = (const float*)d_in[16];
    float* out = (float*)d_out;

    lstm_ae<<<dim3(BATCH / BPB), dim3(BLOCKT), SMEM_BYTES, stream>>>(
        xi, w1ih, w1hh, b1i, b1h, w2ih, w2hh, b2i, b2h,
        w3ih, w3hh, b3i, b3h, w4ih, w4hh, b4i, b4h, out);
}